// Round 3
// baseline (812.559 us; speedup 1.0000x reference)
//
#include <hip/hip_runtime.h>

#define N_NODES 100000
#define N_EDGES 400000
#define N_GRAPHS 2048
#define HID 128
#define NLAYER 4
#define TOUT 5
#define EPSV 1e-5f
#define SLOPE 0.2f

typedef float v4f __attribute__((ext_vector_type(4)));
typedef float v2f __attribute__((ext_vector_type(2)));
typedef __bf16 v8bf __attribute__((ext_vector_type(8)));
typedef short v8s __attribute__((ext_vector_type(8)));

static __device__ __forceinline__ unsigned short f2bf_bits(float f){
  unsigned u = __builtin_bit_cast(unsigned, f);
  unsigned r = u + 0x7fffu + ((u >> 16) & 1u);
  return (unsigned short)(r >> 16);
}
static __device__ __forceinline__ float bfbits2f(unsigned short s){
  unsigned u = ((unsigned)s) << 16;
  return __builtin_bit_cast(float, u);
}

// h = x @ node_w + node_b
__global__ void k_hinit(const float* __restrict__ x, const float* __restrict__ nw,
                        const float* __restrict__ nb, float* __restrict__ hbuf){
  int n = blockIdx.x; int c = threadIdx.x;
  float acc = nb[c];
  #pragma unroll
  for(int f=0; f<7; ++f) acc += x[n*7+f]*nw[f*HID+c];
  hbuf[n*HID+c] = acc;
}

// small projection matrices: Me[3][16], be[16] such that a_e[e][l*4+h] = ea@Me + be
__global__ void k_prep(const float* __restrict__ gat_edge_w, const float* __restrict__ att_edge,
                       const float* __restrict__ edge_w, const float* __restrict__ edge_b,
                       float* __restrict__ mebuf){
  __shared__ float Ve[128*16];
  int t = threadIdx.x;
  for(int id=t; id<2048; id+=256){
    int k = id>>4, li = id&15, l = li>>2, hh = li&3;
    const float* gw = gat_edge_w + l*16384 + k*128 + hh*32;
    const float* at = att_edge + l*128 + hh*32;
    float s = 0.f;
    #pragma unroll
    for(int c=0;c<32;++c) s += gw[c]*at[c];
    Ve[k*16+li] = s;
  }
  __syncthreads();
  if(t < 48){
    int f = t>>4, li = t&15;
    float s=0.f;
    for(int k=0;k<128;++k) s += edge_w[f*128+k]*Ve[k*16+li];
    mebuf[f*16+li] = s;
  } else if (t < 64){
    int li = t-48; float s=0.f;
    for(int k=0;k<128;++k) s += edge_b[k]*Ve[k*16+li];
    mebuf[48+li] = s;
  }
}

// swizzle gat_lin_w into MFMA B-fragment order, split into bf16 hi/lo
__global__ void k_wswz(const float* __restrict__ W, unsigned short* __restrict__ whi,
                       unsigned short* __restrict__ wlo){
  int idx = blockIdx.x*256 + threadIdx.x; // 0..65535 == l*16384 + k*128 + c
  int l = idx>>14, k = (idx>>7)&127, c = idx&127;
  float w = W[idx];
  unsigned short hi = f2bf_bits(w);
  unsigned short lo = f2bf_bits(w - bfbits2f(hi));
  int kb=k>>5, quad=(k>>3)&3, j=k&7, cg=c>>4, r=c&15, lane=quad*16+r;
  int dst = ((l*4+kb)*8+cg)*512 + lane*8 + j;
  whi[dst]=hi; wlo[dst]=lo;
}

// per real edge: a_e for all 4 layers x 4 heads (NO atomics on float data)
__global__ void k_edge(const int* __restrict__ ei, const float* __restrict__ ea,
                       const float* __restrict__ mebuf, float* __restrict__ ae,
                       int* __restrict__ deg){
  int e = blockIdx.x*256 + threadIdx.x;
  if(e >= N_EDGES) return;
  int dst = ei[N_EDGES + e];
  float a0 = ea[e*3], a1 = ea[e*3+1], a2 = ea[e*3+2];
  float v[16];
  #pragma unroll
  for(int i=0;i<16;++i)
    v[i] = mebuf[48+i] + a0*mebuf[i] + a1*mebuf[16+i] + a2*mebuf[32+i];
  v4f* aeo = (v4f*)(ae + (size_t)e*16);
  #pragma unroll
  for(int q=0;q<4;++q){ v4f t = {v[q*4],v[q*4+1],v[q*4+2],v[q*4+3]}; aeo[q]=t; }
  atomicAdd(&deg[dst], 1);
}

// aeloop[n][16] = mean of ae over incoming edges (CSR, no atomics); 16 lanes/node
__global__ void k_aeloop(const float* __restrict__ ae, const int* __restrict__ rowptr,
                         const int* __restrict__ csr_eid, float* __restrict__ aeloop){
  int t = threadIdx.x;
  int node = blockIdx.x*16 + (t>>4);
  if(node >= N_NODES) return;
  int li = t & 15;
  int s = rowptr[node], e = rowptr[node+1];
  float acc = 0.f;
  for(int j=s;j<e;++j) acc += ae[(size_t)csr_eid[j]*16 + li];
  int d = e - s;
  aeloop[node*16+li] = acc / (float)(d>1?d:1);
}

// exclusive scan of deg -> rowptr (3 phases, chunk=1024)
__global__ void k_scan1(const int* __restrict__ deg, int* __restrict__ part){
  __shared__ int s[256];
  int t=threadIdx.x; int base = blockIdx.x*1024 + t*4;
  int sum=0;
  #pragma unroll
  for(int j=0;j<4;++j){ int i=base+j; sum += (i<N_NODES)? deg[i]:0; }
  s[t]=sum; __syncthreads();
  for(int off=128; off>0; off>>=1){ if(t<off) s[t]+=s[t+off]; __syncthreads(); }
  if(t==0) part[blockIdx.x]=s[0];
}
__global__ void k_scan2(int* __restrict__ part, int* __restrict__ rowptr, int nb){
  if(threadIdx.x==0 && blockIdx.x==0){
    int run=0;
    for(int i=0;i<nb;++i){ int v=part[i]; part[i]=run; run+=v; }
    rowptr[N_NODES]=run;
  }
}
__global__ void k_scan3(const int* __restrict__ deg, const int* __restrict__ part, int* __restrict__ rowptr){
  __shared__ int s[256];
  int t=threadIdx.x; int base = blockIdx.x*1024 + t*4;
  int v[4]; int sum=0; int pre[4];
  #pragma unroll
  for(int j=0;j<4;++j){ int i=base+j; v[j]=(i<N_NODES)?deg[i]:0; pre[j]=sum; sum+=v[j]; }
  s[t]=sum; __syncthreads();
  for(int off=1; off<256; off<<=1){
    int xv = (t>=off)? s[t-off]:0; __syncthreads();
    s[t]+=xv; __syncthreads();
  }
  int toff = (t>0)? s[t-1]:0;
  int g = part[blockIdx.x];
  #pragma unroll
  for(int j=0;j<4;++j){ int i=base+j; if(i<N_NODES) rowptr[i]=g+toff+pre[j]; }
}

__global__ void k_fill(const int* __restrict__ ei, const int* __restrict__ rowptr,
                       int* __restrict__ fill, int* __restrict__ csr_src, int* __restrict__ csr_eid){
  int e = blockIdx.x*256+threadIdx.x;
  if(e>=N_EDGES) return;
  int dst = ei[N_EDGES+e];
  int pos = rowptr[dst] + atomicAdd(&fill[dst],1);
  csr_src[pos] = ei[e];
  csr_eid[pos] = e;
}

// xh = h @ gat_lin_w[l]  (split-bf16 MFMA, fp32-class accuracy)
// epilogue: a_s[n,h], a_d[n,h] via quad shuffles
__global__ void k_gemm(const float* __restrict__ hbuf, const unsigned short* __restrict__ whi,
                       const unsigned short* __restrict__ wlo,
                       const float* __restrict__ att_src_l, const float* __restrict__ att_dst_l,
                       float* __restrict__ xh, float* __restrict__ as_, float* __restrict__ ad_){
  int wave = threadIdx.x>>6, lane = threadIdx.x&63;
  int row0 = blockIdx.x*64 + wave*16;
  if(row0 >= N_NODES) return;
  int q = lane>>4, r = lane&15;
  const float* hrow = hbuf + (size_t)(row0 + r)*HID;
  v8bf ahi[4], alo[4];
  #pragma unroll
  for(int kb=0;kb<4;++kb){
    const v4f* p = (const v4f*)(hrow + kb*32 + q*8);
    v4f f0 = p[0], f1 = p[1];
    #pragma unroll
    for(int j=0;j<4;++j){
      unsigned short hi = f2bf_bits(f0[j]);
      unsigned short lo = f2bf_bits(f0[j]-bfbits2f(hi));
      ahi[kb][j] = __builtin_bit_cast(__bf16, hi);
      alo[kb][j] = __builtin_bit_cast(__bf16, lo);
      unsigned short hi2 = f2bf_bits(f1[j]);
      unsigned short lo2 = f2bf_bits(f1[j]-bfbits2f(hi2));
      ahi[kb][j+4] = __builtin_bit_cast(__bf16, hi2);
      alo[kb][j+4] = __builtin_bit_cast(__bf16, lo2);
    }
  }
  v4f acc[8];
  #pragma unroll
  for(int cg=0;cg<8;++cg){
    v4f a = {0.f,0.f,0.f,0.f};
    #pragma unroll
    for(int kb=0;kb<4;++kb){
      v8bf bhi = __builtin_bit_cast(v8bf, *(const v8s*)(whi + ((kb*8+cg)*64 + lane)*8));
      v8bf blo = __builtin_bit_cast(v8bf, *(const v8s*)(wlo + ((kb*8+cg)*64 + lane)*8));
      a = __builtin_amdgcn_mfma_f32_16x16x32_bf16(ahi[kb], bhi, a, 0,0,0);
      a = __builtin_amdgcn_mfma_f32_16x16x32_bf16(ahi[kb], blo, a, 0,0,0);
      a = __builtin_amdgcn_mfma_f32_16x16x32_bf16(alo[kb], bhi, a, 0,0,0);
    }
    acc[cg]=a;
  }
  #pragma unroll
  for(int cg=0;cg<8;++cg){
    #pragma unroll
    for(int reg=0;reg<4;++reg)
      xh[(size_t)(row0 + q*4 + reg)*HID + cg*16 + r] = acc[cg][reg];
  }
  #pragma unroll
  for(int hh=0; hh<4; ++hh){
    float sl = att_src_l[hh*32 + r],  sh2 = att_src_l[hh*32+16+r];
    float dl = att_dst_l[hh*32 + r],  dh  = att_dst_l[hh*32+16+r];
    #pragma unroll
    for(int reg=0;reg<4;++reg){
      float vs = acc[2*hh][reg]*sl + acc[2*hh+1][reg]*sh2;
      float vd = acc[2*hh][reg]*dl + acc[2*hh+1][reg]*dh;
      vs += __shfl_xor(vs,1); vs += __shfl_xor(vs,2); vs += __shfl_xor(vs,4); vs += __shfl_xor(vs,8);
      vd += __shfl_xor(vd,1); vd += __shfl_xor(vd,2); vd += __shfl_xor(vd,4); vd += __shfl_xor(vd,8);
      if(r==0){
        int rr = row0 + q*4 + reg;
        as_[rr*4+hh] = vs;
        ad_[rr*4+hh] = vd;
      }
    }
  }
}

// thread per (node, head): segment softmax -> final normalized coefs in CSR order
__global__ void k_coef(const float* __restrict__ as_, const float* __restrict__ ad_,
    const float* __restrict__ ae, const float* __restrict__ aeloop,
    const int* __restrict__ rowptr, const int* __restrict__ csr_src, const int* __restrict__ csr_eid,
    float* __restrict__ coef, float* __restrict__ coef_self, int layer){
  int tid = blockIdx.x*256 + threadIdx.x;
  if(tid >= N_NODES*4) return;
  int node = tid>>2, h = tid&3;
  float adv = ad_[tid];
  float al = as_[tid] + adv + aeloop[node*16+layer*4+h];
  al = al>0.f ? al : SLOPE*al;
  int s = rowptr[node], e = rowptr[node+1];
  float m = al;
  for(int j=s;j<e;++j){
    int sr = csr_src[j]; int eid = csr_eid[j];
    float b = as_[sr*4+h] + adv + ae[(size_t)eid*16+layer*4+h];
    b = b>0.f ? b : SLOPE*b;
    coef[(size_t)j*4+h] = b;
    m = fmaxf(m,b);
  }
  float d = __expf(al-m);
  for(int j=s;j<e;++j){
    float eb = __expf(coef[(size_t)j*4+h]-m);
    coef[(size_t)j*4+h] = eb;
    d += eb;
  }
  float inv = 1.f/d;
  coef_self[tid] = __expf(al-m)*inv;
  for(int j=s;j<e;++j) coef[(size_t)j*4+h] *= inv;
}

// wave-per-node weighted gather: acc = coef_self*xh[node] + sum coef[j]*xh[src]
// lane covers channels 2*lane, 2*lane+1 (one head per lane); fused bias+BN+relu+residual
__global__ void k_aggr(const float* __restrict__ xh, const float* __restrict__ coef,
    const float* __restrict__ coef_self,
    const int* __restrict__ rowptr, const int* __restrict__ csr_src,
    const float* __restrict__ bias, const float* __restrict__ gamma, const float* __restrict__ beta,
    const float* __restrict__ mean, const float* __restrict__ var,
    float* __restrict__ hbuf){
  int node = blockIdx.x*4 + (threadIdx.x>>6);
  if(node >= N_NODES) return;
  int lane = threadIdx.x & 63;
  int hh = lane>>4;
  const v2f* xh2 = (const v2f*)xh;
  v2f* h2 = (v2f*)hbuf;
  float cs = coef_self[node*4+hh];
  v2f xv = xh2[(size_t)node*64 + lane];
  float a0 = cs*xv.x, a1 = cs*xv.y;
  int s = rowptr[node], e = rowptr[node+1];
  for(int j=s;j<e;++j){
    int sr = csr_src[j];
    float c = coef[(size_t)j*4+hh];
    v2f v = xh2[(size_t)sr*64 + lane];
    a0 += c*v.x; a1 += c*v.y;
  }
  int c0 = lane*2, c1 = lane*2+1;
  float o0 = a0 + bias[c0];
  float o1 = a1 + bias[c1];
  o0 = (o0-mean[c0])*gamma[c0]*rsqrtf(var[c0]+EPSV)+beta[c0];
  o1 = (o1-mean[c1])*gamma[c1]*rsqrtf(var[c1]+EPSV)+beta[c1];
  v2f hres = h2[(size_t)node*64 + lane];
  v2f outv;
  outv.x = fmaxf(o0,0.f)+hres.x;
  outv.y = fmaxf(o1,0.f)+hres.y;
  h2[(size_t)node*64 + lane] = outv;
}

__global__ void k_gptr(const int* __restrict__ batch, int* __restrict__ gptr){
  int g = blockIdx.x*256+threadIdx.x;
  if(g > N_GRAPHS) return;
  int lo=0, hi=N_NODES;
  while(lo<hi){ int mid=(lo+hi)>>1; if(batch[mid] < g) lo=mid+1; else hi=mid; }
  gptr[g]=lo;
}

__global__ void k_pool(const float* __restrict__ hbuf, const int* __restrict__ gptr,
                       float* __restrict__ gfeat){
  int g = blockIdx.x, c = threadIdx.x;
  int s = gptr[g], e = gptr[g+1];
  float sum=0.f, mx=-3.4e38f;
  for(int i=s;i<e;++i){ float v = hbuf[(size_t)i*HID+c]; sum+=v; mx=fmaxf(mx,v); }
  int cnt = e-s;
  float meanv = sum / (float)(cnt>1?cnt:1);
  if(cnt==0) mx=0.f;
  gfeat[g*384 + c] = meanv;
  gfeat[g*384 + 128 + c] = mx;
  gfeat[g*384 + 256 + c] = sum;
}

__global__ void k_head(const float* __restrict__ gfeat, const float* __restrict__ gf,
   const float* __restrict__ gc_w, const float* __restrict__ gc_b,
   const float* __restrict__ gf1_w, const float* __restrict__ gf1_b,
   const float* __restrict__ gf2_w, const float* __restrict__ gf2_b,
   const float* __restrict__ p1_w, const float* __restrict__ p1_b,
   const float* __restrict__ p2_w, const float* __restrict__ p2_b,
   const float* __restrict__ p3_w, const float* __restrict__ p3_b,
   float* __restrict__ out){
  __shared__ float sg[384];
  __shared__ float comb[192];
  __shared__ float hid1[64];
  __shared__ float r1[128];
  __shared__ float r2[64];
  int g = blockIdx.x, t = threadIdx.x;
  for(int i=t;i<384;i+=128) sg[i] = gfeat[g*384+i];
  if(t<64){
    float a = gf1_b[t];
    #pragma unroll
    for(int i=0;i<10;++i) a += gf[g*10+i]*gf1_w[i*64+t];
    hid1[t] = fmaxf(a,0.f);
  }
  __syncthreads();
  if(t<64){
    float a = gf2_b[t];
    for(int k=0;k<64;++k) a += hid1[k]*gf2_w[k*64+t];
    comb[128+t] = a;
  }
  {
    float a = gc_b[t];
    for(int k=0;k<384;++k) a += sg[k]*gc_w[k*128+t];
    comb[t] = fmaxf(a,0.f);
  }
  __syncthreads();
  {
    float a = p1_b[t];
    for(int k=0;k<192;++k) a += comb[k]*p1_w[k*128+t];
    r1[t] = fmaxf(a,0.f);
  }
  __syncthreads();
  if(t<64){
    float a = p2_b[t];
    for(int k=0;k<128;++k) a += r1[k]*p2_w[k*64+t];
    r2[t] = fmaxf(a,0.f);
  }
  __syncthreads();
  if(t<TOUT){
    float a = p3_b[t];
    for(int k=0;k<64;++k) a += r2[k]*p3_w[k*TOUT+t];
    out[g*TOUT+t] = a;
  }
}

extern "C" void kernel_launch(void* const* d_in, const int* in_sizes, int n_in,
                              void* d_out, int out_size, void* d_ws, size_t ws_size,
                              hipStream_t stream){
  (void)in_sizes; (void)n_in; (void)out_size; (void)ws_size;
  const float* x        = (const float*)d_in[0];
  const int*   ei       = (const int*)d_in[1];
  const float* ea       = (const float*)d_in[2];
  const int*   batch    = (const int*)d_in[3];
  const float* gfin     = (const float*)d_in[4];
  const float* node_w   = (const float*)d_in[5];
  const float* node_b   = (const float*)d_in[6];
  const float* edge_w   = (const float*)d_in[7];
  const float* edge_b   = (const float*)d_in[8];
  const float* gat_lin_w  = (const float*)d_in[9];
  const float* gat_edge_w = (const float*)d_in[10];
  const float* att_src  = (const float*)d_in[11];
  const float* att_dst  = (const float*)d_in[12];
  const float* att_edge = (const float*)d_in[13];
  const float* gat_bias = (const float*)d_in[14];
  const float* bn_gamma = (const float*)d_in[15];
  const float* bn_beta  = (const float*)d_in[16];
  const float* bn_mean  = (const float*)d_in[17];
  const float* bn_var   = (const float*)d_in[18];
  const float* gc_w = (const float*)d_in[19];
  const float* gc_b = (const float*)d_in[20];
  const float* gf1_w = (const float*)d_in[21];
  const float* gf1_b = (const float*)d_in[22];
  const float* gf2_w = (const float*)d_in[23];
  const float* gf2_b = (const float*)d_in[24];
  const float* p1_w = (const float*)d_in[25];
  const float* p1_b = (const float*)d_in[26];
  const float* p2_w = (const float*)d_in[27];
  const float* p2_b = (const float*)d_in[28];
  const float* p3_w = (const float*)d_in[29];
  const float* p3_b = (const float*)d_in[30];
  float* out = (float*)d_out;

  char* w = (char*)d_ws;
  size_t o = 0;
  auto carve = [&](size_t bytes)->char*{
    char* p = w + o; o += (bytes + 255) & ~(size_t)255; return p;
  };
  float* xh     = (float*)carve((size_t)N_NODES*HID*4);
  float* hbuf   = (float*)carve((size_t)N_NODES*HID*4);
  float* ae     = (float*)carve((size_t)N_EDGES*16*4);
  float* aeloop = (float*)carve((size_t)N_NODES*16*4);
  float* as_    = (float*)carve((size_t)N_NODES*4*4);
  float* ad_    = (float*)carve((size_t)N_NODES*4*4);
  float* coef   = (float*)carve((size_t)N_EDGES*4*4);
  float* coefs  = (float*)carve((size_t)N_NODES*4*4);
  int* deg      = (int*)carve((size_t)N_NODES*4);
  int* rowptr   = (int*)carve((size_t)(N_NODES+1)*4);
  int* fill     = (int*)carve((size_t)N_NODES*4);
  int* csr_src  = (int*)carve((size_t)N_EDGES*4);
  int* csr_eid  = (int*)carve((size_t)N_EDGES*4);
  int* part     = (int*)carve(1024*4);
  float* mebuf  = (float*)carve(64*4);
  unsigned short* whi = (unsigned short*)carve(65536*2);
  unsigned short* wlo = (unsigned short*)carve(65536*2);
  int* gptr     = (int*)carve((size_t)(N_GRAPHS+1)*4);
  float* gfeat  = (float*)carve((size_t)N_GRAPHS*384*4);

  hipMemsetAsync(deg, 0, (size_t)N_NODES*4, stream);
  hipMemsetAsync(fill, 0, (size_t)N_NODES*4, stream);

  k_prep<<<1,256,0,stream>>>(gat_edge_w, att_edge, edge_w, edge_b, mebuf);
  k_wswz<<<256,256,0,stream>>>(gat_lin_w, whi, wlo);
  k_hinit<<<N_NODES,128,0,stream>>>(x, node_w, node_b, hbuf);
  k_edge<<<(N_EDGES+255)/256,256,0,stream>>>(ei, ea, mebuf, ae, deg);
  int nb = (N_NODES+1023)/1024;
  k_scan1<<<nb,256,0,stream>>>(deg, part);
  k_scan2<<<1,64,0,stream>>>(part, rowptr, nb);
  k_scan3<<<nb,256,0,stream>>>(deg, part, rowptr);
  k_fill<<<(N_EDGES+255)/256,256,0,stream>>>(ei, rowptr, fill, csr_src, csr_eid);
  k_aeloop<<<(N_NODES+15)/16,256,0,stream>>>(ae, rowptr, csr_eid, aeloop);

  for(int l=0;l<NLAYER;++l){
    k_gemm<<<(N_NODES+63)/64,256,0,stream>>>(hbuf, whi + l*16384, wlo + l*16384,
        att_src + l*128, att_dst + l*128, xh, as_, ad_);
    k_coef<<<(N_NODES*4+255)/256,256,0,stream>>>(as_, ad_, ae, aeloop, rowptr, csr_src, csr_eid,
        coef, coefs, l);
    k_aggr<<<(N_NODES+3)/4,256,0,stream>>>(xh, coef, coefs, rowptr, csr_src,
        gat_bias + l*128, bn_gamma + l*128, bn_beta + l*128, bn_mean + l*128, bn_var + l*128,
        hbuf);
  }

  k_gptr<<<(N_GRAPHS+256)/256,256,0,stream>>>(batch, gptr);
  k_pool<<<N_GRAPHS,128,0,stream>>>(hbuf, gptr, gfeat);
  k_head<<<N_GRAPHS,128,0,stream>>>(gfeat, gfin, gc_w, gc_b, gf1_w, gf1_b, gf2_w, gf2_b,
        p1_w, p1_b, p2_w, p2_b, p3_w, p3_b, out);
}

// Round 4
// 701.417 us; speedup vs baseline: 1.1585x; 1.1585x over previous
//
#include <hip/hip_runtime.h>

#define N_NODES 100000
#define N_EDGES 400000
#define N_GRAPHS 2048
#define HID 128
#define NLAYER 4
#define TOUT 5
#define EPSV 1e-5f
#define SLOPE 0.2f
#define MAXDEG 32

typedef float v4f __attribute__((ext_vector_type(4)));
typedef float v2f __attribute__((ext_vector_type(2)));
typedef __bf16 v8bf __attribute__((ext_vector_type(8)));
typedef short v8s __attribute__((ext_vector_type(8)));

static __device__ __forceinline__ unsigned short f2bf_bits(float f){
  unsigned u = __builtin_bit_cast(unsigned, f);
  unsigned r = u + 0x7fffu + ((u >> 16) & 1u);
  return (unsigned short)(r >> 16);
}
static __device__ __forceinline__ float bfbits2f(unsigned short s){
  unsigned u = ((unsigned)s) << 16;
  return __builtin_bit_cast(float, u);
}

// h = x @ node_w + node_b
__global__ void k_hinit(const float* __restrict__ x, const float* __restrict__ nw,
                        const float* __restrict__ nb, float* __restrict__ hbuf){
  int n = blockIdx.x; int c = threadIdx.x;
  float acc = nb[c];
  #pragma unroll
  for(int f=0; f<7; ++f) acc += x[n*7+f]*nw[f*HID+c];
  hbuf[n*HID+c] = acc;
}

// small projection matrices: Me[3][16], be[16] such that a_e[e][l*4+h] = ea@Me + be
__global__ void k_prep(const float* __restrict__ gat_edge_w, const float* __restrict__ att_edge,
                       const float* __restrict__ edge_w, const float* __restrict__ edge_b,
                       float* __restrict__ mebuf){
  __shared__ float Ve[128*16];
  int t = threadIdx.x;
  for(int id=t; id<2048; id+=256){
    int k = id>>4, li = id&15, l = li>>2, hh = li&3;
    const float* gw = gat_edge_w + l*16384 + k*128 + hh*32;
    const float* at = att_edge + l*128 + hh*32;
    float s = 0.f;
    #pragma unroll
    for(int c=0;c<32;++c) s += gw[c]*at[c];
    Ve[k*16+li] = s;
  }
  __syncthreads();
  if(t < 48){
    int f = t>>4, li = t&15;
    float s=0.f;
    for(int k=0;k<128;++k) s += edge_w[f*128+k]*Ve[k*16+li];
    mebuf[f*16+li] = s;
  } else if (t < 64){
    int li = t-48; float s=0.f;
    for(int k=0;k<128;++k) s += edge_b[k]*Ve[k*16+li];
    mebuf[48+li] = s;
  }
}

// swizzle gat_lin_w into MFMA B-fragment order, split into bf16 hi/lo
__global__ void k_wswz(const float* __restrict__ W, unsigned short* __restrict__ whi,
                       unsigned short* __restrict__ wlo){
  int idx = blockIdx.x*256 + threadIdx.x; // 0..65535 == l*16384 + k*128 + c
  int l = idx>>14, k = (idx>>7)&127, c = idx&127;
  float w = W[idx];
  unsigned short hi = f2bf_bits(w);
  unsigned short lo = f2bf_bits(w - bfbits2f(hi));
  int kb=k>>5, quad=(k>>3)&3, j=k&7, cg=c>>4, r=c&15, lane=quad*16+r;
  int dst = ((l*4+kb)*8+cg)*512 + lane*8 + j;
  whi[dst]=hi; wlo[dst]=lo;
}

// per real edge: a_e for all 4 layers x 4 heads (edge order)
__global__ void k_edge(const int* __restrict__ ei, const float* __restrict__ ea,
                       const float* __restrict__ mebuf, float* __restrict__ ae,
                       int* __restrict__ deg){
  int e = blockIdx.x*256 + threadIdx.x;
  if(e >= N_EDGES) return;
  int dst = ei[N_EDGES + e];
  float a0 = ea[e*3], a1 = ea[e*3+1], a2 = ea[e*3+2];
  float v[16];
  #pragma unroll
  for(int i=0;i<16;++i)
    v[i] = mebuf[48+i] + a0*mebuf[i] + a1*mebuf[16+i] + a2*mebuf[32+i];
  v4f* aeo = (v4f*)(ae + (size_t)e*16);
  #pragma unroll
  for(int q=0;q<4;++q){ v4f t = {v[q*4],v[q*4+1],v[q*4+2],v[q*4+3]}; aeo[q]=t; }
  atomicAdd(&deg[dst], 1);
}

// aeloop[n][16] = mean of ae over incoming edges (CSR-contiguous reads)
__global__ void k_aeloop(const float* __restrict__ ae_csr, const int* __restrict__ rowptr,
                         float* __restrict__ aeloop){
  int t = threadIdx.x;
  int node = blockIdx.x*16 + (t>>4);
  if(node >= N_NODES) return;
  int li = t & 15;
  int s = rowptr[node], e = rowptr[node+1];
  float acc = 0.f;
  for(int j=s;j<e;++j) acc += ae_csr[(size_t)j*16 + li];
  int d = e - s;
  aeloop[node*16+li] = acc / (float)(d>1?d:1);
}

// exclusive scan of deg -> rowptr (3 phases, chunk=1024)
__global__ void k_scan1(const int* __restrict__ deg, int* __restrict__ part){
  __shared__ int s[256];
  int t=threadIdx.x; int base = blockIdx.x*1024 + t*4;
  int sum=0;
  #pragma unroll
  for(int j=0;j<4;++j){ int i=base+j; sum += (i<N_NODES)? deg[i]:0; }
  s[t]=sum; __syncthreads();
  for(int off=128; off>0; off>>=1){ if(t<off) s[t]+=s[t+off]; __syncthreads(); }
  if(t==0) part[blockIdx.x]=s[0];
}
__global__ void k_scan2(int* __restrict__ part, int* __restrict__ rowptr, int nb){
  if(threadIdx.x==0 && blockIdx.x==0){
    int run=0;
    for(int i=0;i<nb;++i){ int v=part[i]; part[i]=run; run+=v; }
    rowptr[N_NODES]=run;
  }
}
__global__ void k_scan3(const int* __restrict__ deg, const int* __restrict__ part, int* __restrict__ rowptr){
  __shared__ int s[256];
  int t=threadIdx.x; int base = blockIdx.x*1024 + t*4;
  int v[4]; int sum=0; int pre[4];
  #pragma unroll
  for(int j=0;j<4;++j){ int i=base+j; v[j]=(i<N_NODES)?deg[i]:0; pre[j]=sum; sum+=v[j]; }
  s[t]=sum; __syncthreads();
  for(int off=1; off<256; off<<=1){
    int xv = (t>=off)? s[t-off]:0; __syncthreads();
    s[t]+=xv; __syncthreads();
  }
  int toff = (t>0)? s[t-1]:0;
  int g = part[blockIdx.x];
  #pragma unroll
  for(int j=0;j<4;++j){ int i=base+j; if(i<N_NODES) rowptr[i]=g+toff+pre[j]; }
}

// build CSR: src ids + ae re-ordered into CSR layout (kills csr_eid indirection)
__global__ void k_fill(const int* __restrict__ ei, const int* __restrict__ rowptr,
                       int* __restrict__ fill, int* __restrict__ csr_src,
                       const float* __restrict__ ae, float* __restrict__ ae_csr){
  int e = blockIdx.x*256+threadIdx.x;
  if(e>=N_EDGES) return;
  int dst = ei[N_EDGES+e];
  int pos = rowptr[dst] + atomicAdd(&fill[dst],1);
  csr_src[pos] = ei[e];
  const v4f* sp = (const v4f*)(ae + (size_t)e*16);
  v4f* dp = (v4f*)(ae_csr + (size_t)pos*16);
  dp[0]=sp[0]; dp[1]=sp[1]; dp[2]=sp[2]; dp[3]=sp[3];
}

// xh = h @ gat_lin_w[l]  (split-bf16 MFMA, fp32-class accuracy)
// epilogue: a_s[n,h], a_d[n,h] via quad shuffles
__global__ void k_gemm(const float* __restrict__ hbuf, const unsigned short* __restrict__ whi,
                       const unsigned short* __restrict__ wlo,
                       const float* __restrict__ att_src_l, const float* __restrict__ att_dst_l,
                       float* __restrict__ xh, float* __restrict__ as_, float* __restrict__ ad_){
  int wave = threadIdx.x>>6, lane = threadIdx.x&63;
  int row0 = blockIdx.x*64 + wave*16;
  if(row0 >= N_NODES) return;
  int q = lane>>4, r = lane&15;
  const float* hrow = hbuf + (size_t)(row0 + r)*HID;
  v8bf ahi[4], alo[4];
  #pragma unroll
  for(int kb=0;kb<4;++kb){
    const v4f* p = (const v4f*)(hrow + kb*32 + q*8);
    v4f f0 = p[0], f1 = p[1];
    #pragma unroll
    for(int j=0;j<4;++j){
      unsigned short hi = f2bf_bits(f0[j]);
      unsigned short lo = f2bf_bits(f0[j]-bfbits2f(hi));
      ahi[kb][j] = __builtin_bit_cast(__bf16, hi);
      alo[kb][j] = __builtin_bit_cast(__bf16, lo);
      unsigned short hi2 = f2bf_bits(f1[j]);
      unsigned short lo2 = f2bf_bits(f1[j]-bfbits2f(hi2));
      ahi[kb][j+4] = __builtin_bit_cast(__bf16, hi2);
      alo[kb][j+4] = __builtin_bit_cast(__bf16, lo2);
    }
  }
  v4f acc[8];
  #pragma unroll
  for(int cg=0;cg<8;++cg){
    v4f a = {0.f,0.f,0.f,0.f};
    #pragma unroll
    for(int kb=0;kb<4;++kb){
      v8bf bhi = __builtin_bit_cast(v8bf, *(const v8s*)(whi + ((kb*8+cg)*64 + lane)*8));
      v8bf blo = __builtin_bit_cast(v8bf, *(const v8s*)(wlo + ((kb*8+cg)*64 + lane)*8));
      a = __builtin_amdgcn_mfma_f32_16x16x32_bf16(ahi[kb], bhi, a, 0,0,0);
      a = __builtin_amdgcn_mfma_f32_16x16x32_bf16(ahi[kb], blo, a, 0,0,0);
      a = __builtin_amdgcn_mfma_f32_16x16x32_bf16(alo[kb], bhi, a, 0,0,0);
    }
    acc[cg]=a;
  }
  #pragma unroll
  for(int cg=0;cg<8;++cg){
    #pragma unroll
    for(int reg=0;reg<4;++reg)
      xh[(size_t)(row0 + q*4 + reg)*HID + cg*16 + r] = acc[cg][reg];
  }
  #pragma unroll
  for(int hh=0; hh<4; ++hh){
    float sl = att_src_l[hh*32 + r],  sh2 = att_src_l[hh*32+16+r];
    float dl = att_dst_l[hh*32 + r],  dh  = att_dst_l[hh*32+16+r];
    #pragma unroll
    for(int reg=0;reg<4;++reg){
      float vs = acc[2*hh][reg]*sl + acc[2*hh+1][reg]*sh2;
      float vd = acc[2*hh][reg]*dl + acc[2*hh+1][reg]*dh;
      vs += __shfl_xor(vs,1); vs += __shfl_xor(vs,2); vs += __shfl_xor(vs,4); vs += __shfl_xor(vs,8);
      vd += __shfl_xor(vd,1); vd += __shfl_xor(vd,2); vd += __shfl_xor(vd,4); vd += __shfl_xor(vd,8);
      if(r==0){
        int rr = row0 + q*4 + reg;
        as_[rr*4+hh] = vs;
        ad_[rr*4+hh] = vd;
      }
    }
  }
}

// wave-per-node: phase A computes normalized softmax coefs in parallel
// (lane = eidx*4 + h, segment reduce via shfl_xor over eidx bits), parks them
// in wave-private LDS; phase B is a x4-unrolled weighted row gather.
// Fused bias+BN+relu+residual epilogue.
__global__ void k_aggr(const float* __restrict__ xh, const float* __restrict__ as_,
    const float* __restrict__ ad_, const float* __restrict__ ae_csr, const float* __restrict__ aeloop,
    const int* __restrict__ rowptr, const int* __restrict__ csr_src,
    const float* __restrict__ bias, const float* __restrict__ gamma, const float* __restrict__ beta,
    const float* __restrict__ mean, const float* __restrict__ var,
    float* __restrict__ hbuf, int layer){
  __shared__ float lds_coef[4][MAXDEG*4];
  __shared__ int   lds_src[4][MAXDEG];
  int w = threadIdx.x>>6, lane = threadIdx.x&63;
  int node = blockIdx.x*4 + w;
  if(node >= N_NODES) return;
  int s = rowptr[node], e = rowptr[node+1];
  int deg = e - s;
  const v2f* xh2 = (const v2f*)xh;
  v2f* h2 = (v2f*)hbuf;
  int hh = lane>>4;
  float a0, a1;

  if(deg <= MAXDEG){
    // ---- phase A: parallel softmax coefs ----
    int eidx = lane>>2, h = lane&3;
    float ad_h = ad_[node*4+h];
    float al = as_[node*4+h] + ad_h + aeloop[node*16+layer*4+h];
    al = al>0.f ? al : SLOPE*al;
    int j0 = eidx, j1 = 16+eidx;
    float b0 = -1e30f, b1 = -1e30f;
    if(j0 < deg){
      int sr = csr_src[s+j0];
      if(h==0) lds_src[w][j0] = sr;
      float b = as_[sr*4+h] + ad_h + ae_csr[(size_t)(s+j0)*16+layer*4+h];
      b0 = b>0.f ? b : SLOPE*b;
    }
    if(j1 < deg){
      int sr = csr_src[s+j1];
      if(h==0) lds_src[w][j1] = sr;
      float b = as_[sr*4+h] + ad_h + ae_csr[(size_t)(s+j1)*16+layer*4+h];
      b1 = b>0.f ? b : SLOPE*b;
    }
    float m = fmaxf(al, fmaxf(b0,b1));
    m = fmaxf(m, __shfl_xor(m,4)); m = fmaxf(m, __shfl_xor(m,8));
    m = fmaxf(m, __shfl_xor(m,16)); m = fmaxf(m, __shfl_xor(m,32));
    float e0 = (j0<deg)? __expf(b0-m) : 0.f;
    float e1 = (j1<deg)? __expf(b1-m) : 0.f;
    float ds = e0+e1;
    ds += __shfl_xor(ds,4); ds += __shfl_xor(ds,8);
    ds += __shfl_xor(ds,16); ds += __shfl_xor(ds,32);
    float es = __expf(al-m);
    float inv = 1.f/(ds+es);
    float cs = es*inv;
    if(j0<deg) lds_coef[w][j0*4+h] = e0*inv;
    if(j1<deg) lds_coef[w][j1*4+h] = e1*inv;
    // ---- phase B: weighted gather (x4 unroll, independent loads) ----
    float csb = __shfl(cs, hh);   // lanes 0..3 hold cs for h=0..3
    v2f xv = xh2[(size_t)node*64 + lane];
    a0 = csb*xv.x; a1 = csb*xv.y;
    int j = 0;
    for(; j+4<=deg; j+=4){
      float c0 = lds_coef[w][(j  )*4+hh];
      float c1 = lds_coef[w][(j+1)*4+hh];
      float c2 = lds_coef[w][(j+2)*4+hh];
      float c3 = lds_coef[w][(j+3)*4+hh];
      int s0 = lds_src[w][j], s1 = lds_src[w][j+1], s2 = lds_src[w][j+2], s3 = lds_src[w][j+3];
      v2f v0 = xh2[(size_t)s0*64+lane];
      v2f v1 = xh2[(size_t)s1*64+lane];
      v2f v2 = xh2[(size_t)s2*64+lane];
      v2f v3 = xh2[(size_t)s3*64+lane];
      a0 += c0*v0.x + c1*v1.x + c2*v2.x + c3*v3.x;
      a1 += c0*v0.y + c1*v1.y + c2*v2.y + c3*v3.y;
    }
    for(; j<deg; ++j){
      float c = lds_coef[w][j*4+hh];
      int sr = lds_src[w][j];
      v2f v = xh2[(size_t)sr*64+lane];
      a0 += c*v.x; a1 += c*v.y;
    }
  } else {
    // fallback (deg > MAXDEG, ~never taken): serial online softmax
    float adv = ad_[node*4+hh];
    float al = as_[node*4+hh] + adv + aeloop[node*16+layer*4+hh];
    al = al>0.f ? al : SLOPE*al;
    float m = al, d = 1.f;
    v2f xv = xh2[(size_t)node*64 + lane];
    float acc0 = xv.x, acc1 = xv.y;
    for(int j=s;j<e;++j){
      int sr = csr_src[j];
      float b = as_[sr*4+hh] + adv + ae_csr[(size_t)j*16+layer*4+hh];
      b = b>0.f?b:SLOPE*b;
      v2f v = xh2[(size_t)sr*64 + lane];
      float nm = fmaxf(m,b);
      float sc = __expf(m-nm), eb = __expf(b-nm);
      d = d*sc + eb;
      acc0 = acc0*sc + eb*v.x; acc1 = acc1*sc + eb*v.y;
      m = nm;
    }
    float inv = 1.f/d;
    a0 = acc0*inv; a1 = acc1*inv;
  }

  int c0 = lane*2, c1 = lane*2+1;
  float o0 = a0 + bias[c0];
  float o1 = a1 + bias[c1];
  o0 = (o0-mean[c0])*gamma[c0]*rsqrtf(var[c0]+EPSV)+beta[c0];
  o1 = (o1-mean[c1])*gamma[c1]*rsqrtf(var[c1]+EPSV)+beta[c1];
  v2f hres = h2[(size_t)node*64 + lane];
  v2f outv;
  outv.x = fmaxf(o0,0.f)+hres.x;
  outv.y = fmaxf(o1,0.f)+hres.y;
  h2[(size_t)node*64 + lane] = outv;
}

__global__ void k_gptr(const int* __restrict__ batch, int* __restrict__ gptr){
  int g = blockIdx.x*256+threadIdx.x;
  if(g > N_GRAPHS) return;
  int lo=0, hi=N_NODES;
  while(lo<hi){ int mid=(lo+hi)>>1; if(batch[mid] < g) lo=mid+1; else hi=mid; }
  gptr[g]=lo;
}

__global__ void k_pool(const float* __restrict__ hbuf, const int* __restrict__ gptr,
                       float* __restrict__ gfeat){
  int g = blockIdx.x, c = threadIdx.x;
  int s = gptr[g], e = gptr[g+1];
  float sum=0.f, mx=-3.4e38f;
  for(int i=s;i<e;++i){ float v = hbuf[(size_t)i*HID+c]; sum+=v; mx=fmaxf(mx,v); }
  int cnt = e-s;
  float meanv = sum / (float)(cnt>1?cnt:1);
  if(cnt==0) mx=0.f;
  gfeat[g*384 + c] = meanv;
  gfeat[g*384 + 128 + c] = mx;
  gfeat[g*384 + 256 + c] = sum;
}

__global__ void k_head(const float* __restrict__ gfeat, const float* __restrict__ gf,
   const float* __restrict__ gc_w, const float* __restrict__ gc_b,
   const float* __restrict__ gf1_w, const float* __restrict__ gf1_b,
   const float* __restrict__ gf2_w, const float* __restrict__ gf2_b,
   const float* __restrict__ p1_w, const float* __restrict__ p1_b,
   const float* __restrict__ p2_w, const float* __restrict__ p2_b,
   const float* __restrict__ p3_w, const float* __restrict__ p3_b,
   float* __restrict__ out){
  __shared__ float sg[384];
  __shared__ float comb[192];
  __shared__ float hid1[64];
  __shared__ float r1[128];
  __shared__ float r2[64];
  int g = blockIdx.x, t = threadIdx.x;
  for(int i=t;i<384;i+=128) sg[i] = gfeat[g*384+i];
  if(t<64){
    float a = gf1_b[t];
    #pragma unroll
    for(int i=0;i<10;++i) a += gf[g*10+i]*gf1_w[i*64+t];
    hid1[t] = fmaxf(a,0.f);
  }
  __syncthreads();
  if(t<64){
    float a = gf2_b[t];
    for(int k=0;k<64;++k) a += hid1[k]*gf2_w[k*64+t];
    comb[128+t] = a;
  }
  {
    float a = gc_b[t];
    for(int k=0;k<384;++k) a += sg[k]*gc_w[k*128+t];
    comb[t] = fmaxf(a,0.f);
  }
  __syncthreads();
  {
    float a = p1_b[t];
    for(int k=0;k<192;++k) a += comb[k]*p1_w[k*128+t];
    r1[t] = fmaxf(a,0.f);
  }
  __syncthreads();
  if(t<64){
    float a = p2_b[t];
    for(int k=0;k<128;++k) a += r1[k]*p2_w[k*64+t];
    r2[t] = fmaxf(a,0.f);
  }
  __syncthreads();
  if(t<TOUT){
    float a = p3_b[t];
    for(int k=0;k<64;++k) a += r2[k]*p3_w[k*TOUT+t];
    out[g*TOUT+t] = a;
  }
}

extern "C" void kernel_launch(void* const* d_in, const int* in_sizes, int n_in,
                              void* d_out, int out_size, void* d_ws, size_t ws_size,
                              hipStream_t stream){
  (void)in_sizes; (void)n_in; (void)out_size; (void)ws_size;
  const float* x        = (const float*)d_in[0];
  const int*   ei       = (const int*)d_in[1];
  const float* ea       = (const float*)d_in[2];
  const int*   batch    = (const int*)d_in[3];
  const float* gfin     = (const float*)d_in[4];
  const float* node_w   = (const float*)d_in[5];
  const float* node_b   = (const float*)d_in[6];
  const float* edge_w   = (const float*)d_in[7];
  const float* edge_b   = (const float*)d_in[8];
  const float* gat_lin_w  = (const float*)d_in[9];
  const float* gat_edge_w = (const float*)d_in[10];
  const float* att_src  = (const float*)d_in[11];
  const float* att_dst  = (const float*)d_in[12];
  const float* att_edge = (const float*)d_in[13];
  const float* gat_bias = (const float*)d_in[14];
  const float* bn_gamma = (const float*)d_in[15];
  const float* bn_beta  = (const float*)d_in[16];
  const float* bn_mean  = (const float*)d_in[17];
  const float* bn_var   = (const float*)d_in[18];
  const float* gc_w = (const float*)d_in[19];
  const float* gc_b = (const float*)d_in[20];
  const float* gf1_w = (const float*)d_in[21];
  const float* gf1_b = (const float*)d_in[22];
  const float* gf2_w = (const float*)d_in[23];
  const float* gf2_b = (const float*)d_in[24];
  const float* p1_w = (const float*)d_in[25];
  const float* p1_b = (const float*)d_in[26];
  const float* p2_w = (const float*)d_in[27];
  const float* p2_b = (const float*)d_in[28];
  const float* p3_w = (const float*)d_in[29];
  const float* p3_b = (const float*)d_in[30];
  float* out = (float*)d_out;

  char* w = (char*)d_ws;
  size_t o = 0;
  auto carve = [&](size_t bytes)->char*{
    char* p = w + o; o += (bytes + 255) & ~(size_t)255; return p;
  };
  float* xh     = (float*)carve((size_t)N_NODES*HID*4);
  float* hbuf   = (float*)carve((size_t)N_NODES*HID*4);
  float* ae     = (float*)carve((size_t)N_EDGES*16*4);
  float* ae_csr = (float*)carve((size_t)N_EDGES*16*4);
  float* aeloop = (float*)carve((size_t)N_NODES*16*4);
  float* as_    = (float*)carve((size_t)N_NODES*4*4);
  float* ad_    = (float*)carve((size_t)N_NODES*4*4);
  int* deg      = (int*)carve((size_t)N_NODES*4);
  int* rowptr   = (int*)carve((size_t)(N_NODES+1)*4);
  int* fill     = (int*)carve((size_t)N_NODES*4);
  int* csr_src  = (int*)carve((size_t)N_EDGES*4);
  int* part     = (int*)carve(1024*4);
  float* mebuf  = (float*)carve(64*4);
  unsigned short* whi = (unsigned short*)carve(65536*2);
  unsigned short* wlo = (unsigned short*)carve(65536*2);
  int* gptr     = (int*)carve((size_t)(N_GRAPHS+1)*4);
  float* gfeat  = (float*)carve((size_t)N_GRAPHS*384*4);

  hipMemsetAsync(deg, 0, (size_t)N_NODES*4, stream);
  hipMemsetAsync(fill, 0, (size_t)N_NODES*4, stream);

  k_prep<<<1,256,0,stream>>>(gat_edge_w, att_edge, edge_w, edge_b, mebuf);
  k_wswz<<<256,256,0,stream>>>(gat_lin_w, whi, wlo);
  k_hinit<<<N_NODES,128,0,stream>>>(x, node_w, node_b, hbuf);
  k_edge<<<(N_EDGES+255)/256,256,0,stream>>>(ei, ea, mebuf, ae, deg);
  int nb = (N_NODES+1023)/1024;
  k_scan1<<<nb,256,0,stream>>>(deg, part);
  k_scan2<<<1,64,0,stream>>>(part, rowptr, nb);
  k_scan3<<<nb,256,0,stream>>>(deg, part, rowptr);
  k_fill<<<(N_EDGES+255)/256,256,0,stream>>>(ei, rowptr, fill, csr_src, ae, ae_csr);
  k_aeloop<<<(N_NODES+15)/16,256,0,stream>>>(ae_csr, rowptr, aeloop);

  for(int l=0;l<NLAYER;++l){
    k_gemm<<<(N_NODES+63)/64,256,0,stream>>>(hbuf, whi + l*16384, wlo + l*16384,
        att_src + l*128, att_dst + l*128, xh, as_, ad_);
    k_aggr<<<(N_NODES+3)/4,256,0,stream>>>(xh, as_, ad_, ae_csr, aeloop, rowptr, csr_src,
        gat_bias + l*128, bn_gamma + l*128, bn_beta + l*128, bn_mean + l*128, bn_var + l*128,
        hbuf, l);
  }

  k_gptr<<<(N_GRAPHS+256)/256,256,0,stream>>>(batch, gptr);
  k_pool<<<N_GRAPHS,128,0,stream>>>(hbuf, gptr, gfeat);
  k_head<<<N_GRAPHS,128,0,stream>>>(gfeat, gfin, gc_w, gc_b, gf1_w, gf1_b, gf2_w, gf2_b,
        p1_w, p1_b, p2_w, p2_b, p3_w, p3_b, out);
}

// Round 5
// 661.609 us; speedup vs baseline: 1.2282x; 1.0602x over previous
//
#include <hip/hip_runtime.h>

#define N_NODES 100000
#define N_EDGES 400000
#define N_GRAPHS 2048
#define HID 128
#define NLAYER 4
#define TOUT 5
#define EPSV 1e-5f
#define SLOPE 0.2f
#define MAXDEG 32

typedef float v4f __attribute__((ext_vector_type(4)));
typedef float v2f __attribute__((ext_vector_type(2)));
typedef __bf16 v8bf __attribute__((ext_vector_type(8)));
typedef short v8s __attribute__((ext_vector_type(8)));

static __device__ __forceinline__ unsigned short f2bf_bits(float f){
  unsigned u = __builtin_bit_cast(unsigned, f);
  unsigned r = u + 0x7fffu + ((u >> 16) & 1u);
  return (unsigned short)(r >> 16);
}
static __device__ __forceinline__ float bfbits2f(unsigned short s){
  unsigned u = ((unsigned)s) << 16;
  return __builtin_bit_cast(float, u);
}
static __device__ __forceinline__ float bflo(unsigned u){
  return __builtin_bit_cast(float, u << 16);
}
static __device__ __forceinline__ float bfhi(unsigned u){
  return __builtin_bit_cast(float, u & 0xffff0000u);
}

// h = x @ node_w + node_b
__global__ void k_hinit(const float* __restrict__ x, const float* __restrict__ nw,
                        const float* __restrict__ nb, float* __restrict__ hbuf){
  int n = blockIdx.x; int c = threadIdx.x;
  float acc = nb[c];
  #pragma unroll
  for(int f=0; f<7; ++f) acc += x[n*7+f]*nw[f*HID+c];
  hbuf[n*HID+c] = acc;
}

// small projection matrices: Me[3][16], be[16] such that a_e[e][l*4+h] = ea@Me + be
__global__ void k_prep(const float* __restrict__ gat_edge_w, const float* __restrict__ att_edge,
                       const float* __restrict__ edge_w, const float* __restrict__ edge_b,
                       float* __restrict__ mebuf){
  __shared__ float Ve[128*16];
  int t = threadIdx.x;
  for(int id=t; id<2048; id+=256){
    int k = id>>4, li = id&15, l = li>>2, hh = li&3;
    const float* gw = gat_edge_w + l*16384 + k*128 + hh*32;
    const float* at = att_edge + l*128 + hh*32;
    float s = 0.f;
    #pragma unroll
    for(int c=0;c<32;++c) s += gw[c]*at[c];
    Ve[k*16+li] = s;
  }
  __syncthreads();
  if(t < 48){
    int f = t>>4, li = t&15;
    float s=0.f;
    for(int k=0;k<128;++k) s += edge_w[f*128+k]*Ve[k*16+li];
    mebuf[f*16+li] = s;
  } else if (t < 64){
    int li = t-48; float s=0.f;
    for(int k=0;k<128;++k) s += edge_b[k]*Ve[k*16+li];
    mebuf[48+li] = s;
  }
}

// swizzle gat_lin_w into MFMA B-fragment order, split into bf16 hi/lo
__global__ void k_wswz(const float* __restrict__ W, unsigned short* __restrict__ whi,
                       unsigned short* __restrict__ wlo){
  int idx = blockIdx.x*256 + threadIdx.x; // 0..65535 == l*16384 + k*128 + c
  int l = idx>>14, k = (idx>>7)&127, c = idx&127;
  float w = W[idx];
  unsigned short hi = f2bf_bits(w);
  unsigned short lo = f2bf_bits(w - bfbits2f(hi));
  int kb=k>>5, quad=(k>>3)&3, j=k&7, cg=c>>4, r=c&15, lane=quad*16+r;
  int dst = ((l*4+kb)*8+cg)*512 + lane*8 + j;
  whi[dst]=hi; wlo[dst]=lo;
}

// per real edge: a_e for all 4 layers x 4 heads (edge order)
__global__ void k_edge(const int* __restrict__ ei, const float* __restrict__ ea,
                       const float* __restrict__ mebuf, float* __restrict__ ae,
                       int* __restrict__ deg){
  int e = blockIdx.x*256 + threadIdx.x;
  if(e >= N_EDGES) return;
  int dst = ei[N_EDGES + e];
  float a0 = ea[e*3], a1 = ea[e*3+1], a2 = ea[e*3+2];
  float v[16];
  #pragma unroll
  for(int i=0;i<16;++i)
    v[i] = mebuf[48+i] + a0*mebuf[i] + a1*mebuf[16+i] + a2*mebuf[32+i];
  v4f* aeo = (v4f*)(ae + (size_t)e*16);
  #pragma unroll
  for(int q=0;q<4;++q){ v4f t = {v[q*4],v[q*4+1],v[q*4+2],v[q*4+3]}; aeo[q]=t; }
  atomicAdd(&deg[dst], 1);
}

// aeloop (layer-major): aeloop[l][n][4] = mean of ae over incoming edges
__global__ void k_aeloop(const float* __restrict__ ae_csr, const int* __restrict__ rowptr,
                         float* __restrict__ aeloop){
  int t = threadIdx.x;
  int node = blockIdx.x*16 + (t>>4);
  if(node >= N_NODES) return;
  int li = t & 15;
  int l = li>>2, h = li&3;
  const float* base = ae_csr + (size_t)l*N_EDGES*4;
  int s = rowptr[node], e = rowptr[node+1];
  float acc = 0.f;
  for(int j=s;j<e;++j) acc += base[(size_t)j*4 + h];
  int d = e - s;
  aeloop[(size_t)l*N_NODES*4 + node*4 + h] = acc / (float)(d>1?d:1);
}

// exclusive scan of deg -> rowptr (3 phases, chunk=1024)
__global__ void k_scan1(const int* __restrict__ deg, int* __restrict__ part){
  __shared__ int s[256];
  int t=threadIdx.x; int base = blockIdx.x*1024 + t*4;
  int sum=0;
  #pragma unroll
  for(int j=0;j<4;++j){ int i=base+j; sum += (i<N_NODES)? deg[i]:0; }
  s[t]=sum; __syncthreads();
  for(int off=128; off>0; off>>=1){ if(t<off) s[t]+=s[t+off]; __syncthreads(); }
  if(t==0) part[blockIdx.x]=s[0];
}
__global__ void k_scan2(int* __restrict__ part, int* __restrict__ rowptr, int nb){
  if(threadIdx.x==0 && blockIdx.x==0){
    int run=0;
    for(int i=0;i<nb;++i){ int v=part[i]; part[i]=run; run+=v; }
    rowptr[N_NODES]=run;
  }
}
__global__ void k_scan3(const int* __restrict__ deg, const int* __restrict__ part, int* __restrict__ rowptr){
  __shared__ int s[256];
  int t=threadIdx.x; int base = blockIdx.x*1024 + t*4;
  int v[4]; int sum=0; int pre[4];
  #pragma unroll
  for(int j=0;j<4;++j){ int i=base+j; v[j]=(i<N_NODES)?deg[i]:0; pre[j]=sum; sum+=v[j]; }
  s[t]=sum; __syncthreads();
  for(int off=1; off<256; off<<=1){
    int xv = (t>=off)? s[t-off]:0; __syncthreads();
    s[t]+=xv; __syncthreads();
  }
  int toff = (t>0)? s[t-1]:0;
  int g = part[blockIdx.x];
  #pragma unroll
  for(int j=0;j<4;++j){ int i=base+j; if(i<N_NODES) rowptr[i]=g+toff+pre[j]; }
}

// build CSR: src ids + ae re-ordered into LAYER-MAJOR CSR layout
__global__ void k_fill(const int* __restrict__ ei, const int* __restrict__ rowptr,
                       int* __restrict__ fill, int* __restrict__ csr_src,
                       const float* __restrict__ ae, float* __restrict__ ae_csr){
  int e = blockIdx.x*256+threadIdx.x;
  if(e>=N_EDGES) return;
  int dst = ei[N_EDGES+e];
  int pos = rowptr[dst] + atomicAdd(&fill[dst],1);
  csr_src[pos] = ei[e];
  const v4f* sp = (const v4f*)(ae + (size_t)e*16);
  #pragma unroll
  for(int l=0;l<4;++l)
    ((v4f*)(ae_csr + (size_t)l*N_EDGES*4))[pos] = sp[l];
}

// xh = h @ gat_lin_w[l]  (split-bf16 MFMA, fp32-class accuracy)
// writes xh in bf16 packed (uint = channels 2c,2c+1); epilogue a_s/a_d via shuffles
__global__ void k_gemm(const float* __restrict__ hbuf, const unsigned short* __restrict__ whi,
                       const unsigned short* __restrict__ wlo,
                       const float* __restrict__ att_src_l, const float* __restrict__ att_dst_l,
                       unsigned* __restrict__ xhb, float* __restrict__ as_, float* __restrict__ ad_){
  int wave = threadIdx.x>>6, lane = threadIdx.x&63;
  int row0 = blockIdx.x*64 + wave*16;
  if(row0 >= N_NODES) return;
  int q = lane>>4, r = lane&15;
  const float* hrow = hbuf + (size_t)(row0 + r)*HID;
  v8bf ahi[4], alo[4];
  #pragma unroll
  for(int kb=0;kb<4;++kb){
    const v4f* p = (const v4f*)(hrow + kb*32 + q*8);
    v4f f0 = p[0], f1 = p[1];
    #pragma unroll
    for(int j=0;j<4;++j){
      unsigned short hi = f2bf_bits(f0[j]);
      unsigned short lo = f2bf_bits(f0[j]-bfbits2f(hi));
      ahi[kb][j] = __builtin_bit_cast(__bf16, hi);
      alo[kb][j] = __builtin_bit_cast(__bf16, lo);
      unsigned short hi2 = f2bf_bits(f1[j]);
      unsigned short lo2 = f2bf_bits(f1[j]-bfbits2f(hi2));
      ahi[kb][j+4] = __builtin_bit_cast(__bf16, hi2);
      alo[kb][j+4] = __builtin_bit_cast(__bf16, lo2);
    }
  }
  v4f acc[8];
  #pragma unroll
  for(int cg=0;cg<8;++cg){
    v4f a = {0.f,0.f,0.f,0.f};
    #pragma unroll
    for(int kb=0;kb<4;++kb){
      v8bf bhi = __builtin_bit_cast(v8bf, *(const v8s*)(whi + ((kb*8+cg)*64 + lane)*8));
      v8bf blo = __builtin_bit_cast(v8bf, *(const v8s*)(wlo + ((kb*8+cg)*64 + lane)*8));
      a = __builtin_amdgcn_mfma_f32_16x16x32_bf16(ahi[kb], bhi, a, 0,0,0);
      a = __builtin_amdgcn_mfma_f32_16x16x32_bf16(ahi[kb], blo, a, 0,0,0);
      a = __builtin_amdgcn_mfma_f32_16x16x32_bf16(alo[kb], bhi, a, 0,0,0);
    }
    acc[cg]=a;
  }
  // pack col pairs via lane exchange: lane r (even) packs cols (cg*16+r, +1)
  #pragma unroll
  for(int cg=0;cg<8;++cg){
    #pragma unroll
    for(int reg=0;reg<4;++reg){
      float v = acc[cg][reg];
      float o = __shfl_xor(v, 1);
      if((r&1)==0){
        unsigned pack = (unsigned)f2bf_bits(v) | ((unsigned)f2bf_bits(o)<<16);
        xhb[(size_t)(row0 + q*4 + reg)*64 + ((cg*16+r)>>1)] = pack;
      }
    }
  }
  #pragma unroll
  for(int hh=0; hh<4; ++hh){
    float sl = att_src_l[hh*32 + r],  sh2 = att_src_l[hh*32+16+r];
    float dl = att_dst_l[hh*32 + r],  dh  = att_dst_l[hh*32+16+r];
    #pragma unroll
    for(int reg=0;reg<4;++reg){
      float vs = acc[2*hh][reg]*sl + acc[2*hh+1][reg]*sh2;
      float vd = acc[2*hh][reg]*dl + acc[2*hh+1][reg]*dh;
      vs += __shfl_xor(vs,1); vs += __shfl_xor(vs,2); vs += __shfl_xor(vs,4); vs += __shfl_xor(vs,8);
      vd += __shfl_xor(vd,1); vd += __shfl_xor(vd,2); vd += __shfl_xor(vd,4); vd += __shfl_xor(vd,8);
      if(r==0){
        int rr = row0 + q*4 + reg;
        as_[rr*4+hh] = vs;
        ad_[rr*4+hh] = vd;
      }
    }
  }
}

// wave-per-node: phase A parallel softmax coefs (lane=eidx*4+h, shfl reduce),
// phase B x4-unrolled bf16 row gather. Fused bias+BN+relu+residual.
// ae_l / aeloop_l are layer-major slices.
__global__ void k_aggr(const unsigned* __restrict__ xhb, const float* __restrict__ as_,
    const float* __restrict__ ad_, const float* __restrict__ ae_l, const float* __restrict__ aeloop_l,
    const int* __restrict__ rowptr, const int* __restrict__ csr_src,
    const float* __restrict__ bias, const float* __restrict__ gamma, const float* __restrict__ beta,
    const float* __restrict__ mean, const float* __restrict__ var,
    float* __restrict__ hbuf){
  __shared__ float lds_coef[4][MAXDEG*4];
  __shared__ int   lds_src[4][MAXDEG];
  int w = threadIdx.x>>6, lane = threadIdx.x&63;
  int node = blockIdx.x*4 + w;
  if(node >= N_NODES) return;
  int s = rowptr[node], e = rowptr[node+1];
  int deg = e - s;
  v2f* h2 = (v2f*)hbuf;
  int hh = lane>>4;
  float a0, a1;

  if(deg <= MAXDEG){
    // ---- phase A: parallel softmax coefs ----
    int eidx = lane>>2, h = lane&3;
    float ad_h = ad_[node*4+h];
    float al = as_[node*4+h] + ad_h + aeloop_l[node*4+h];
    al = al>0.f ? al : SLOPE*al;
    int j0 = eidx, j1 = 16+eidx;
    float b0 = -1e30f, b1 = -1e30f;
    if(j0 < deg){
      int sr = csr_src[s+j0];
      if(h==0) lds_src[w][j0] = sr;
      float b = as_[sr*4+h] + ad_h + ae_l[(size_t)(s+j0)*4+h];
      b0 = b>0.f ? b : SLOPE*b;
    }
    if(j1 < deg){
      int sr = csr_src[s+j1];
      if(h==0) lds_src[w][j1] = sr;
      float b = as_[sr*4+h] + ad_h + ae_l[(size_t)(s+j1)*4+h];
      b1 = b>0.f ? b : SLOPE*b;
    }
    float m = fmaxf(al, fmaxf(b0,b1));
    m = fmaxf(m, __shfl_xor(m,4)); m = fmaxf(m, __shfl_xor(m,8));
    m = fmaxf(m, __shfl_xor(m,16)); m = fmaxf(m, __shfl_xor(m,32));
    float e0 = (j0<deg)? __expf(b0-m) : 0.f;
    float e1 = (j1<deg)? __expf(b1-m) : 0.f;
    float ds = e0+e1;
    ds += __shfl_xor(ds,4); ds += __shfl_xor(ds,8);
    ds += __shfl_xor(ds,16); ds += __shfl_xor(ds,32);
    float es = __expf(al-m);
    float inv = 1.f/(ds+es);
    float cs = es*inv;
    if(j0<deg) lds_coef[w][j0*4+h] = e0*inv;
    if(j1<deg) lds_coef[w][j1*4+h] = e1*inv;
    // ---- phase B: bf16 weighted gather (x4 unroll) ----
    float csb = __shfl(cs, hh);
    unsigned u = xhb[(size_t)node*64 + lane];
    a0 = csb*bflo(u); a1 = csb*bfhi(u);
    int j = 0;
    for(; j+4<=deg; j+=4){
      float c0 = lds_coef[w][(j  )*4+hh];
      float c1 = lds_coef[w][(j+1)*4+hh];
      float c2 = lds_coef[w][(j+2)*4+hh];
      float c3 = lds_coef[w][(j+3)*4+hh];
      int s0 = lds_src[w][j], s1 = lds_src[w][j+1], s2 = lds_src[w][j+2], s3 = lds_src[w][j+3];
      unsigned u0 = xhb[(size_t)s0*64+lane];
      unsigned u1 = xhb[(size_t)s1*64+lane];
      unsigned u2 = xhb[(size_t)s2*64+lane];
      unsigned u3 = xhb[(size_t)s3*64+lane];
      a0 += c0*bflo(u0) + c1*bflo(u1) + c2*bflo(u2) + c3*bflo(u3);
      a1 += c0*bfhi(u0) + c1*bfhi(u1) + c2*bfhi(u2) + c3*bfhi(u3);
    }
    for(; j<deg; ++j){
      float c = lds_coef[w][j*4+hh];
      int sr = lds_src[w][j];
      unsigned uv = xhb[(size_t)sr*64+lane];
      a0 += c*bflo(uv); a1 += c*bfhi(uv);
    }
  } else {
    // fallback (deg > MAXDEG): serial online softmax
    float adv = ad_[node*4+hh];
    float al = as_[node*4+hh] + adv + aeloop_l[node*4+hh];
    al = al>0.f ? al : SLOPE*al;
    float m = al, d = 1.f;
    unsigned u = xhb[(size_t)node*64 + lane];
    float acc0 = bflo(u), acc1 = bfhi(u);
    for(int j=s;j<e;++j){
      int sr = csr_src[j];
      float b = as_[sr*4+hh] + adv + ae_l[(size_t)j*4+hh];
      b = b>0.f?b:SLOPE*b;
      unsigned uv = xhb[(size_t)sr*64 + lane];
      float nm = fmaxf(m,b);
      float sc = __expf(m-nm), eb = __expf(b-nm);
      d = d*sc + eb;
      acc0 = acc0*sc + eb*bflo(uv); acc1 = acc1*sc + eb*bfhi(uv);
      m = nm;
    }
    float inv = 1.f/d;
    a0 = acc0*inv; a1 = acc1*inv;
  }

  int c0 = lane*2, c1 = lane*2+1;
  float o0 = a0 + bias[c0];
  float o1 = a1 + bias[c1];
  o0 = (o0-mean[c0])*gamma[c0]*rsqrtf(var[c0]+EPSV)+beta[c0];
  o1 = (o1-mean[c1])*gamma[c1]*rsqrtf(var[c1]+EPSV)+beta[c1];
  v2f hres = h2[(size_t)node*64 + lane];
  v2f outv;
  outv.x = fmaxf(o0,0.f)+hres.x;
  outv.y = fmaxf(o1,0.f)+hres.y;
  h2[(size_t)node*64 + lane] = outv;
}

__global__ void k_gptr(const int* __restrict__ batch, int* __restrict__ gptr){
  int g = blockIdx.x*256+threadIdx.x;
  if(g > N_GRAPHS) return;
  int lo=0, hi=N_NODES;
  while(lo<hi){ int mid=(lo+hi)>>1; if(batch[mid] < g) lo=mid+1; else hi=mid; }
  gptr[g]=lo;
}

__global__ void k_pool(const float* __restrict__ hbuf, const int* __restrict__ gptr,
                       float* __restrict__ gfeat){
  int g = blockIdx.x, c = threadIdx.x;
  int s = gptr[g], e = gptr[g+1];
  float sum=0.f, mx=-3.4e38f;
  for(int i=s;i<e;++i){ float v = hbuf[(size_t)i*HID+c]; sum+=v; mx=fmaxf(mx,v); }
  int cnt = e-s;
  float meanv = sum / (float)(cnt>1?cnt:1);
  if(cnt==0) mx=0.f;
  gfeat[g*384 + c] = meanv;
  gfeat[g*384 + 128 + c] = mx;
  gfeat[g*384 + 256 + c] = sum;
}

__global__ void k_head(const float* __restrict__ gfeat, const float* __restrict__ gf,
   const float* __restrict__ gc_w, const float* __restrict__ gc_b,
   const float* __restrict__ gf1_w, const float* __restrict__ gf1_b,
   const float* __restrict__ gf2_w, const float* __restrict__ gf2_b,
   const float* __restrict__ p1_w, const float* __restrict__ p1_b,
   const float* __restrict__ p2_w, const float* __restrict__ p2_b,
   const float* __restrict__ p3_w, const float* __restrict__ p3_b,
   float* __restrict__ out){
  __shared__ float sg[384];
  __shared__ float comb[192];
  __shared__ float hid1[64];
  __shared__ float r1[128];
  __shared__ float r2[64];
  int g = blockIdx.x, t = threadIdx.x;
  for(int i=t;i<384;i+=128) sg[i] = gfeat[g*384+i];
  if(t<64){
    float a = gf1_b[t];
    #pragma unroll
    for(int i=0;i<10;++i) a += gf[g*10+i]*gf1_w[i*64+t];
    hid1[t] = fmaxf(a,0.f);
  }
  __syncthreads();
  if(t<64){
    float a = gf2_b[t];
    for(int k=0;k<64;++k) a += hid1[k]*gf2_w[k*64+t];
    comb[128+t] = a;
  }
  {
    float a = gc_b[t];
    for(int k=0;k<384;++k) a += sg[k]*gc_w[k*128+t];
    comb[t] = fmaxf(a,0.f);
  }
  __syncthreads();
  {
    float a = p1_b[t];
    for(int k=0;k<192;++k) a += comb[k]*p1_w[k*128+t];
    r1[t] = fmaxf(a,0.f);
  }
  __syncthreads();
  if(t<64){
    float a = p2_b[t];
    for(int k=0;k<128;++k) a += r1[k]*p2_w[k*64+t];
    r2[t] = fmaxf(a,0.f);
  }
  __syncthreads();
  if(t<TOUT){
    float a = p3_b[t];
    for(int k=0;k<64;++k) a += r2[k]*p3_w[k*TOUT+t];
    out[g*TOUT+t] = a;
  }
}

extern "C" void kernel_launch(void* const* d_in, const int* in_sizes, int n_in,
                              void* d_out, int out_size, void* d_ws, size_t ws_size,
                              hipStream_t stream){
  (void)in_sizes; (void)n_in; (void)out_size; (void)ws_size;
  const float* x        = (const float*)d_in[0];
  const int*   ei       = (const int*)d_in[1];
  const float* ea       = (const float*)d_in[2];
  const int*   batch    = (const int*)d_in[3];
  const float* gfin     = (const float*)d_in[4];
  const float* node_w   = (const float*)d_in[5];
  const float* node_b   = (const float*)d_in[6];
  const float* edge_w   = (const float*)d_in[7];
  const float* edge_b   = (const float*)d_in[8];
  const float* gat_lin_w  = (const float*)d_in[9];
  const float* gat_edge_w = (const float*)d_in[10];
  const float* att_src  = (const float*)d_in[11];
  const float* att_dst  = (const float*)d_in[12];
  const float* att_edge = (const float*)d_in[13];
  const float* gat_bias = (const float*)d_in[14];
  const float* bn_gamma = (const float*)d_in[15];
  const float* bn_beta  = (const float*)d_in[16];
  const float* bn_mean  = (const float*)d_in[17];
  const float* bn_var   = (const float*)d_in[18];
  const float* gc_w = (const float*)d_in[19];
  const float* gc_b = (const float*)d_in[20];
  const float* gf1_w = (const float*)d_in[21];
  const float* gf1_b = (const float*)d_in[22];
  const float* gf2_w = (const float*)d_in[23];
  const float* gf2_b = (const float*)d_in[24];
  const float* p1_w = (const float*)d_in[25];
  const float* p1_b = (const float*)d_in[26];
  const float* p2_w = (const float*)d_in[27];
  const float* p2_b = (const float*)d_in[28];
  const float* p3_w = (const float*)d_in[29];
  const float* p3_b = (const float*)d_in[30];
  float* out = (float*)d_out;

  char* w = (char*)d_ws;
  size_t o = 0;
  auto carve = [&](size_t bytes)->char*{
    char* p = w + o; o += (bytes + 255) & ~(size_t)255; return p;
  };
  unsigned* xhb = (unsigned*)carve((size_t)N_NODES*64*4);
  float* hbuf   = (float*)carve((size_t)N_NODES*HID*4);
  float* ae     = (float*)carve((size_t)N_EDGES*16*4);
  float* ae_csr = (float*)carve((size_t)N_EDGES*16*4);
  float* aeloop = (float*)carve((size_t)N_NODES*16*4);
  float* as_    = (float*)carve((size_t)N_NODES*4*4);
  float* ad_    = (float*)carve((size_t)N_NODES*4*4);
  int* deg      = (int*)carve((size_t)N_NODES*4);
  int* rowptr   = (int*)carve((size_t)(N_NODES+1)*4);
  int* fill     = (int*)carve((size_t)N_NODES*4);
  int* csr_src  = (int*)carve((size_t)N_EDGES*4);
  int* part     = (int*)carve(1024*4);
  float* mebuf  = (float*)carve(64*4);
  unsigned short* whi = (unsigned short*)carve(65536*2);
  unsigned short* wlo = (unsigned short*)carve(65536*2);
  int* gptr     = (int*)carve((size_t)(N_GRAPHS+1)*4);
  float* gfeat  = (float*)carve((size_t)N_GRAPHS*384*4);

  hipMemsetAsync(deg, 0, (size_t)N_NODES*4, stream);
  hipMemsetAsync(fill, 0, (size_t)N_NODES*4, stream);

  k_prep<<<1,256,0,stream>>>(gat_edge_w, att_edge, edge_w, edge_b, mebuf);
  k_wswz<<<256,256,0,stream>>>(gat_lin_w, whi, wlo);
  k_hinit<<<N_NODES,128,0,stream>>>(x, node_w, node_b, hbuf);
  k_edge<<<(N_EDGES+255)/256,256,0,stream>>>(ei, ea, mebuf, ae, deg);
  int nb = (N_NODES+1023)/1024;
  k_scan1<<<nb,256,0,stream>>>(deg, part);
  k_scan2<<<1,64,0,stream>>>(part, rowptr, nb);
  k_scan3<<<nb,256,0,stream>>>(deg, part, rowptr);
  k_fill<<<(N_EDGES+255)/256,256,0,stream>>>(ei, rowptr, fill, csr_src, ae, ae_csr);
  k_aeloop<<<(N_NODES+15)/16,256,0,stream>>>(ae_csr, rowptr, aeloop);

  for(int l=0;l<NLAYER;++l){
    k_gemm<<<(N_NODES+63)/64,256,0,stream>>>(hbuf, whi + l*16384, wlo + l*16384,
        att_src + l*128, att_dst + l*128, xhb, as_, ad_);
    k_aggr<<<(N_NODES+3)/4,256,0,stream>>>(xhb, as_, ad_,
        ae_csr + (size_t)l*N_EDGES*4, aeloop + (size_t)l*N_NODES*4,
        rowptr, csr_src,
        gat_bias + l*128, bn_gamma + l*128, bn_beta + l*128, bn_mean + l*128, bn_var + l*128,
        hbuf);
  }

  k_gptr<<<(N_GRAPHS+256)/256,256,0,stream>>>(batch, gptr);
  k_pool<<<N_GRAPHS,128,0,stream>>>(hbuf, gptr, gfeat);
  k_head<<<N_GRAPHS,128,0,stream>>>(gfeat, gfin, gc_w, gc_b, gf1_w, gf1_b, gf2_w, gf2_b,
        p1_w, p1_b, p2_w, p2_b, p3_w, p3_b, out);
}

// Round 6
// 636.606 us; speedup vs baseline: 1.2764x; 1.0393x over previous
//
#include <hip/hip_runtime.h>

#define N_NODES 100000
#define N_EDGES 400000
#define N_GRAPHS 2048
#define HID 128
#define NLAYER 4
#define TOUT 5
#define EPSV 1e-5f
#define SLOPE 0.2f
#define MAXDEG 32

typedef float v4f __attribute__((ext_vector_type(4)));
typedef float v2f __attribute__((ext_vector_type(2)));
typedef __bf16 v8bf __attribute__((ext_vector_type(8)));
typedef short v8s __attribute__((ext_vector_type(8)));

static __device__ __forceinline__ unsigned short f2bf_bits(float f){
  unsigned u = __builtin_bit_cast(unsigned, f);
  unsigned r = u + 0x7fffu + ((u >> 16) & 1u);
  return (unsigned short)(r >> 16);
}
static __device__ __forceinline__ float bfbits2f(unsigned short s){
  unsigned u = ((unsigned)s) << 16;
  return __builtin_bit_cast(float, u);
}
static __device__ __forceinline__ float bflo(unsigned u){
  return __builtin_bit_cast(float, u << 16);
}
static __device__ __forceinline__ float bfhi(unsigned u){
  return __builtin_bit_cast(float, u & 0xffff0000u);
}
static __device__ __forceinline__ float lrelu(float v){
  return v>0.f ? v : SLOPE*v;
}

// h = x @ node_w + node_b
__global__ void k_hinit(const float* __restrict__ x, const float* __restrict__ nw,
                        const float* __restrict__ nb, float* __restrict__ hbuf){
  int n = blockIdx.x; int c = threadIdx.x;
  float acc = nb[c];
  #pragma unroll
  for(int f=0; f<7; ++f) acc += x[n*7+f]*nw[f*HID+c];
  hbuf[n*HID+c] = acc;
}

// small projection matrices: Me[3][16], be[16] such that a_e[e][l*4+h] = ea@Me + be
__global__ void k_prep(const float* __restrict__ gat_edge_w, const float* __restrict__ att_edge,
                       const float* __restrict__ edge_w, const float* __restrict__ edge_b,
                       float* __restrict__ mebuf){
  __shared__ float Ve[128*16];
  int t = threadIdx.x;
  for(int id=t; id<2048; id+=256){
    int k = id>>4, li = id&15, l = li>>2, hh = li&3;
    const float* gw = gat_edge_w + l*16384 + k*128 + hh*32;
    const float* at = att_edge + l*128 + hh*32;
    float s = 0.f;
    #pragma unroll
    for(int c=0;c<32;++c) s += gw[c]*at[c];
    Ve[k*16+li] = s;
  }
  __syncthreads();
  if(t < 48){
    int f = t>>4, li = t&15;
    float s=0.f;
    for(int k=0;k<128;++k) s += edge_w[f*128+k]*Ve[k*16+li];
    mebuf[f*16+li] = s;
  } else if (t < 64){
    int li = t-48; float s=0.f;
    for(int k=0;k<128;++k) s += edge_b[k]*Ve[k*16+li];
    mebuf[48+li] = s;
  }
}

// fold BN: A = gamma/sqrt(var+eps); S = (bias-mean)*A + beta   (both [L][128] flat)
__global__ void k_bnfold(const float* __restrict__ gat_bias, const float* __restrict__ gamma,
                         const float* __restrict__ beta, const float* __restrict__ mean,
                         const float* __restrict__ var, float* __restrict__ bnA,
                         float* __restrict__ bnS){
  int t = blockIdx.x*256 + threadIdx.x;
  if(t >= NLAYER*HID) return;
  float A = gamma[t]*rsqrtf(var[t]+EPSV);
  bnA[t] = A;
  bnS[t] = (gat_bias[t]-mean[t])*A + beta[t];
}

// swizzle gat_lin_w into MFMA B-fragment order, split into bf16 hi/lo
__global__ void k_wswz(const float* __restrict__ W, unsigned short* __restrict__ whi,
                       unsigned short* __restrict__ wlo){
  int idx = blockIdx.x*256 + threadIdx.x; // 0..65535 == l*16384 + k*128 + c
  int l = idx>>14, k = (idx>>7)&127, c = idx&127;
  float w = W[idx];
  unsigned short hi = f2bf_bits(w);
  unsigned short lo = f2bf_bits(w - bfbits2f(hi));
  int kb=k>>5, quad=(k>>3)&3, j=k&7, cg=c>>4, r=c&15, lane=quad*16+r;
  int dst = ((l*4+kb)*8+cg)*512 + lane*8 + j;
  whi[dst]=hi; wlo[dst]=lo;
}

__global__ void k_deg(const int* __restrict__ ei, int* __restrict__ deg){
  int e = blockIdx.x*256 + threadIdx.x;
  if(e >= N_EDGES) return;
  atomicAdd(&deg[ei[N_EDGES+e]], 1);
}

// exclusive scan of deg -> rowptr (3 phases, chunk=1024)
__global__ void k_scan1(const int* __restrict__ deg, int* __restrict__ part){
  __shared__ int s[256];
  int t=threadIdx.x; int base = blockIdx.x*1024 + t*4;
  int sum=0;
  #pragma unroll
  for(int j=0;j<4;++j){ int i=base+j; sum += (i<N_NODES)? deg[i]:0; }
  s[t]=sum; __syncthreads();
  for(int off=128; off>0; off>>=1){ if(t<off) s[t]+=s[t+off]; __syncthreads(); }
  if(t==0) part[blockIdx.x]=s[0];
}
__global__ void k_scan2(int* __restrict__ part, int* __restrict__ rowptr, int nb){
  if(threadIdx.x==0 && blockIdx.x==0){
    int run=0;
    for(int i=0;i<nb;++i){ int v=part[i]; part[i]=run; run+=v; }
    rowptr[N_NODES]=run;
  }
}
__global__ void k_scan3(const int* __restrict__ deg, const int* __restrict__ part, int* __restrict__ rowptr){
  __shared__ int s[256];
  int t=threadIdx.x; int base = blockIdx.x*1024 + t*4;
  int v[4]; int sum=0; int pre[4];
  #pragma unroll
  for(int j=0;j<4;++j){ int i=base+j; v[j]=(i<N_NODES)?deg[i]:0; pre[j]=sum; sum+=v[j]; }
  s[t]=sum; __syncthreads();
  for(int off=1; off<256; off<<=1){
    int xv = (t>=off)? s[t-off]:0; __syncthreads();
    s[t]+=xv; __syncthreads();
  }
  int toff = (t>0)? s[t-1]:0;
  int g = part[blockIdx.x];
  #pragma unroll
  for(int j=0;j<4;++j){ int i=base+j; if(i<N_NODES) rowptr[i]=g+toff+pre[j]; }
}

// build CSR: src ids + edge_attr reordered (3 floats per edge)
__global__ void k_fill(const int* __restrict__ ei, const float* __restrict__ ea,
                       const int* __restrict__ rowptr, int* __restrict__ fill,
                       int* __restrict__ csr_src, float* __restrict__ ea_csr){
  int e = blockIdx.x*256+threadIdx.x;
  if(e>=N_EDGES) return;
  int dst = ei[N_EDGES+e];
  int pos = rowptr[dst] + atomicAdd(&fill[dst],1);
  csr_src[pos] = ei[e];
  ea_csr[(size_t)pos*3  ] = ea[e*3];
  ea_csr[(size_t)pos*3+1] = ea[e*3+1];
  ea_csr[(size_t)pos*3+2] = ea[e*3+2];
}

// eamean[n][4] = mean of edge_attr over incoming edges (0 if none)
__global__ void k_eamean(const float* __restrict__ ea_csr, const int* __restrict__ rowptr,
                         float* __restrict__ eamean){
  int n = blockIdx.x*256+threadIdx.x;
  if(n>=N_NODES) return;
  int s = rowptr[n], e = rowptr[n+1];
  float a0=0.f,a1=0.f,a2=0.f;
  for(int j=s;j<e;++j){
    a0 += ea_csr[(size_t)j*3];
    a1 += ea_csr[(size_t)j*3+1];
    a2 += ea_csr[(size_t)j*3+2];
  }
  int d = e-s;
  float inv = 1.f/(float)(d>1?d:1);
  eamean[n*4  ]=a0*inv;
  eamean[n*4+1]=a1*inv;
  eamean[n*4+2]=a2*inv;
  eamean[n*4+3]=(d>0)?1.f:0.f;   // validity flag for self-loop affine term
}

// xh = h @ gat_lin_w[l]  (split-bf16 MFMA) -> bf16-packed xhb; epilogue a_s/a_d
__global__ void k_gemm(const float* __restrict__ hbuf, const unsigned short* __restrict__ whi,
                       const unsigned short* __restrict__ wlo,
                       const float* __restrict__ att_src_l, const float* __restrict__ att_dst_l,
                       unsigned* __restrict__ xhb, float* __restrict__ as_, float* __restrict__ ad_){
  int wave = threadIdx.x>>6, lane = threadIdx.x&63;
  int row0 = blockIdx.x*64 + wave*16;
  if(row0 >= N_NODES) return;
  int q = lane>>4, r = lane&15;
  const float* hrow = hbuf + (size_t)(row0 + r)*HID;
  v8bf ahi[4], alo[4];
  #pragma unroll
  for(int kb=0;kb<4;++kb){
    const v4f* p = (const v4f*)(hrow + kb*32 + q*8);
    v4f f0 = p[0], f1 = p[1];
    #pragma unroll
    for(int j=0;j<4;++j){
      unsigned short hi = f2bf_bits(f0[j]);
      unsigned short lo = f2bf_bits(f0[j]-bfbits2f(hi));
      ahi[kb][j] = __builtin_bit_cast(__bf16, hi);
      alo[kb][j] = __builtin_bit_cast(__bf16, lo);
      unsigned short hi2 = f2bf_bits(f1[j]);
      unsigned short lo2 = f2bf_bits(f1[j]-bfbits2f(hi2));
      ahi[kb][j+4] = __builtin_bit_cast(__bf16, hi2);
      alo[kb][j+4] = __builtin_bit_cast(__bf16, lo2);
    }
  }
  v4f acc[8];
  #pragma unroll
  for(int cg=0;cg<8;++cg){
    v4f a = {0.f,0.f,0.f,0.f};
    #pragma unroll
    for(int kb=0;kb<4;++kb){
      v8bf bhi = __builtin_bit_cast(v8bf, *(const v8s*)(whi + ((kb*8+cg)*64 + lane)*8));
      v8bf blo = __builtin_bit_cast(v8bf, *(const v8s*)(wlo + ((kb*8+cg)*64 + lane)*8));
      a = __builtin_amdgcn_mfma_f32_16x16x32_bf16(ahi[kb], bhi, a, 0,0,0);
      a = __builtin_amdgcn_mfma_f32_16x16x32_bf16(ahi[kb], blo, a, 0,0,0);
      a = __builtin_amdgcn_mfma_f32_16x16x32_bf16(alo[kb], bhi, a, 0,0,0);
    }
    acc[cg]=a;
  }
  #pragma unroll
  for(int cg=0;cg<8;++cg){
    #pragma unroll
    for(int reg=0;reg<4;++reg){
      float v = acc[cg][reg];
      float o = __shfl_xor(v, 1);
      if((r&1)==0){
        unsigned pack = (unsigned)f2bf_bits(v) | ((unsigned)f2bf_bits(o)<<16);
        xhb[(size_t)(row0 + q*4 + reg)*64 + ((cg*16+r)>>1)] = pack;
      }
    }
  }
  #pragma unroll
  for(int hh=0; hh<4; ++hh){
    float sl = att_src_l[hh*32 + r],  sh2 = att_src_l[hh*32+16+r];
    float dl = att_dst_l[hh*32 + r],  dh  = att_dst_l[hh*32+16+r];
    #pragma unroll
    for(int reg=0;reg<4;++reg){
      float vs = acc[2*hh][reg]*sl + acc[2*hh+1][reg]*sh2;
      float vd = acc[2*hh][reg]*dl + acc[2*hh+1][reg]*dh;
      vs += __shfl_xor(vs,1); vs += __shfl_xor(vs,2); vs += __shfl_xor(vs,4); vs += __shfl_xor(vs,8);
      vd += __shfl_xor(vd,1); vd += __shfl_xor(vd,2); vd += __shfl_xor(vd,4); vd += __shfl_xor(vd,8);
      if(r==0){
        int rr = row0 + q*4 + reg;
        as_[rr*4+hh] = vs;
        ad_[rr*4+hh] = vd;
      }
    }
  }
}

// wave-per-node. Phase A: parallel softmax coefs (lane = eidx*4+h), a_e computed
// on the fly from ea_csr (affine). Phase B: half-wave-per-edge uint2 gather
// (lane owns 4 channels), 2 edge-pairs in flight, combine via shfl_xor(·,32).
// Epilogue: folded BN (A,S) + relu + residual, v4f by 32 lanes.
__global__ void k_aggr(const unsigned* __restrict__ xhb, const float* __restrict__ as_,
    const float* __restrict__ ad_, const float* __restrict__ ea_csr,
    const float* __restrict__ eamean, const float* __restrict__ mebuf,
    const int* __restrict__ rowptr, const int* __restrict__ csr_src,
    const float* __restrict__ bnA_l, const float* __restrict__ bnS_l,
    float* __restrict__ hbuf, int layer){
  __shared__ float lds_coef[4][MAXDEG*4];
  __shared__ int   lds_src[4][MAXDEG];
  __shared__ float sme[64];
  int w = threadIdx.x>>6, lane = threadIdx.x&63;
  if(threadIdx.x < 64) sme[threadIdx.x] = mebuf[threadIdx.x];
  __syncthreads();
  int node = blockIdx.x*4 + w;
  if(node >= N_NODES) return;
  int s = rowptr[node], e = rowptr[node+1];
  int deg = e - s;
  int l = lane&31, half = lane>>5, hh2 = l>>3;
  const uint2* xrow = (const uint2*)xhb;
  float a0,a1,a2,a3;

  if(deg <= MAXDEG){
    // ---- phase A ----
    int eidx = lane>>2, h = lane&3;
    int li = layer*4+h;
    float mec0=sme[li], mec1=sme[16+li], mec2=sme[32+li], meb=sme[48+li];
    float ad_h = ad_[node*4+h];
    float lt = eamean[node*4]*mec0 + eamean[node*4+1]*mec1 + eamean[node*4+2]*mec2 + meb;
    float al = lrelu(as_[node*4+h] + ad_h + eamean[node*4+3]*lt);
    int j0 = eidx, j1 = 16+eidx;
    float b0 = -1e30f, b1 = -1e30f;
    int s0 = node, s1 = node;
    if(j0 < deg){
      s0 = csr_src[s+j0];
      float q0=ea_csr[(size_t)(s+j0)*3], q1=ea_csr[(size_t)(s+j0)*3+1], q2=ea_csr[(size_t)(s+j0)*3+2];
      b0 = lrelu(as_[s0*4+h] + ad_h + q0*mec0+q1*mec1+q2*mec2+meb);
    }
    if(j1 < deg){
      s1 = csr_src[s+j1];
      float q0=ea_csr[(size_t)(s+j1)*3], q1=ea_csr[(size_t)(s+j1)*3+1], q2=ea_csr[(size_t)(s+j1)*3+2];
      b1 = lrelu(as_[s1*4+h] + ad_h + q0*mec0+q1*mec1+q2*mec2+meb);
    }
    if(h==0){ lds_src[w][j0]=s0; lds_src[w][j1]=s1; }
    float m = fmaxf(al, fmaxf(b0,b1));
    m = fmaxf(m, __shfl_xor(m,4)); m = fmaxf(m, __shfl_xor(m,8));
    m = fmaxf(m, __shfl_xor(m,16)); m = fmaxf(m, __shfl_xor(m,32));
    float e0 = (j0<deg)? __expf(b0-m) : 0.f;
    float e1 = (j1<deg)? __expf(b1-m) : 0.f;
    float ds = e0+e1;
    ds += __shfl_xor(ds,4); ds += __shfl_xor(ds,8);
    ds += __shfl_xor(ds,16); ds += __shfl_xor(ds,32);
    float es = __expf(al-m);
    float inv = 1.f/(ds+es);
    float cs = es*inv;
    lds_coef[w][j0*4+h] = e0*inv;
    lds_coef[w][j1*4+h] = e1*inv;
    // ---- phase B ----
    float cs4 = __shfl(cs, hh2);
    uint2 su = xrow[(size_t)node*32 + l];
    int pdeg = (deg+3)&~3;
    a0=a1=a2=a3=0.f;
    for(int j=0;j<pdeg;j+=4){
      float ca = lds_coef[w][(j+half)*4+hh2];
      float cb = lds_coef[w][(j+2+half)*4+hh2];
      int sa = lds_src[w][j+half], sb = lds_src[w][j+2+half];
      uint2 ua = xrow[(size_t)sa*32+l];
      uint2 ub = xrow[(size_t)sb*32+l];
      a0 += ca*bflo(ua.x) + cb*bflo(ub.x);
      a1 += ca*bfhi(ua.x) + cb*bfhi(ub.x);
      a2 += ca*bflo(ua.y) + cb*bflo(ub.y);
      a3 += ca*bfhi(ua.y) + cb*bfhi(ub.y);
    }
    a0 += __shfl_xor(a0,32); a1 += __shfl_xor(a1,32);
    a2 += __shfl_xor(a2,32); a3 += __shfl_xor(a3,32);
    a0 += cs4*bflo(su.x); a1 += cs4*bfhi(su.x);
    a2 += cs4*bflo(su.y); a3 += cs4*bfhi(su.y);
  } else {
    // fallback (deg > MAXDEG): serial online softmax, each lane 4 channels
    int li = layer*4+hh2;
    float mec0=sme[li], mec1=sme[16+li], mec2=sme[32+li], meb=sme[48+li];
    float adv = ad_[node*4+hh2];
    float lt = eamean[node*4]*mec0 + eamean[node*4+1]*mec1 + eamean[node*4+2]*mec2 + meb;
    float al = lrelu(as_[node*4+hh2] + adv + eamean[node*4+3]*lt);
    float m = al, d = 1.f;
    uint2 su = xrow[(size_t)node*32 + l];
    float c0=bflo(su.x),c1=bfhi(su.x),c2=bflo(su.y),c3=bfhi(su.y);
    for(int j=s;j<e;++j){
      int sr = csr_src[j];
      float q0=ea_csr[(size_t)j*3], q1=ea_csr[(size_t)j*3+1], q2=ea_csr[(size_t)j*3+2];
      float b = lrelu(as_[sr*4+hh2] + adv + q0*mec0+q1*mec1+q2*mec2+meb);
      uint2 uv = xrow[(size_t)sr*32 + l];
      float nm = fmaxf(m,b);
      float sc = __expf(m-nm), eb = __expf(b-nm);
      d = d*sc + eb;
      c0 = c0*sc + eb*bflo(uv.x); c1 = c1*sc + eb*bfhi(uv.x);
      c2 = c2*sc + eb*bflo(uv.y); c3 = c3*sc + eb*bfhi(uv.y);
      m = nm;
    }
    float inv = 1.f/d;
    a0=c0*inv; a1=c1*inv; a2=c2*inv; a3=c3*inv;
  }

  if(half==0){
    const v4f* A4 = (const v4f*)bnA_l;
    const v4f* S4 = (const v4f*)bnS_l;
    v4f A = A4[l], S = S4[l];
    v4f* h4 = (v4f*)hbuf;
    v4f hres = h4[(size_t)node*32 + l];
    v4f o;
    o.x = fmaxf(a0*A.x+S.x, 0.f) + hres.x;
    o.y = fmaxf(a1*A.y+S.y, 0.f) + hres.y;
    o.z = fmaxf(a2*A.z+S.z, 0.f) + hres.z;
    o.w = fmaxf(a3*A.w+S.w, 0.f) + hres.w;
    h4[(size_t)node*32 + l] = o;
  }
}

__global__ void k_gptr(const int* __restrict__ batch, int* __restrict__ gptr){
  int g = blockIdx.x*256+threadIdx.x;
  if(g > N_GRAPHS) return;
  int lo=0, hi=N_NODES;
  while(lo<hi){ int mid=(lo+hi)>>1; if(batch[mid] < g) lo=mid+1; else hi=mid; }
  gptr[g]=lo;
}

__global__ void k_pool(const float* __restrict__ hbuf, const int* __restrict__ gptr,
                       float* __restrict__ gfeat){
  int g = blockIdx.x, c = threadIdx.x;
  int s = gptr[g], e = gptr[g+1];
  float sum=0.f, mx=-3.4e38f;
  for(int i=s;i<e;++i){ float v = hbuf[(size_t)i*HID+c]; sum+=v; mx=fmaxf(mx,v); }
  int cnt = e-s;
  float meanv = sum / (float)(cnt>1?cnt:1);
  if(cnt==0) mx=0.f;
  gfeat[g*384 + c] = meanv;
  gfeat[g*384 + 128 + c] = mx;
  gfeat[g*384 + 256 + c] = sum;
}

__global__ void k_head(const float* __restrict__ gfeat, const float* __restrict__ gf,
   const float* __restrict__ gc_w, const float* __restrict__ gc_b,
   const float* __restrict__ gf1_w, const float* __restrict__ gf1_b,
   const float* __restrict__ gf2_w, const float* __restrict__ gf2_b,
   const float* __restrict__ p1_w, const float* __restrict__ p1_b,
   const float* __restrict__ p2_w, const float* __restrict__ p2_b,
   const float* __restrict__ p3_w, const float* __restrict__ p3_b,
   float* __restrict__ out){
  __shared__ float sg[384];
  __shared__ float comb[192];
  __shared__ float hid1[64];
  __shared__ float r1[128];
  __shared__ float r2[64];
  int g = blockIdx.x, t = threadIdx.x;
  for(int i=t;i<384;i+=128) sg[i] = gfeat[g*384+i];
  if(t<64){
    float a = gf1_b[t];
    #pragma unroll
    for(int i=0;i<10;++i) a += gf[g*10+i]*gf1_w[i*64+t];
    hid1[t] = fmaxf(a,0.f);
  }
  __syncthreads();
  if(t<64){
    float a = gf2_b[t];
    for(int k=0;k<64;++k) a += hid1[k]*gf2_w[k*64+t];
    comb[128+t] = a;
  }
  {
    float a = gc_b[t];
    for(int k=0;k<384;++k) a += sg[k]*gc_w[k*128+t];
    comb[t] = fmaxf(a,0.f);
  }
  __syncthreads();
  {
    float a = p1_b[t];
    for(int k=0;k<192;++k) a += comb[k]*p1_w[k*128+t];
    r1[t] = fmaxf(a,0.f);
  }
  __syncthreads();
  if(t<64){
    float a = p2_b[t];
    for(int k=0;k<128;++k) a += r1[k]*p2_w[k*64+t];
    r2[t] = fmaxf(a,0.f);
  }
  __syncthreads();
  if(t<TOUT){
    float a = p3_b[t];
    for(int k=0;k<64;++k) a += r2[k]*p3_w[k*TOUT+t];
    out[g*TOUT+t] = a;
  }
}

extern "C" void kernel_launch(void* const* d_in, const int* in_sizes, int n_in,
                              void* d_out, int out_size, void* d_ws, size_t ws_size,
                              hipStream_t stream){
  (void)in_sizes; (void)n_in; (void)out_size; (void)ws_size;
  const float* x        = (const float*)d_in[0];
  const int*   ei       = (const int*)d_in[1];
  const float* ea       = (const float*)d_in[2];
  const int*   batch    = (const int*)d_in[3];
  const float* gfin     = (const float*)d_in[4];
  const float* node_w   = (const float*)d_in[5];
  const float* node_b   = (const float*)d_in[6];
  const float* edge_w   = (const float*)d_in[7];
  const float* edge_b   = (const float*)d_in[8];
  const float* gat_lin_w  = (const float*)d_in[9];
  const float* gat_edge_w = (const float*)d_in[10];
  const float* att_src  = (const float*)d_in[11];
  const float* att_dst  = (const float*)d_in[12];
  const float* att_edge = (const float*)d_in[13];
  const float* gat_bias = (const float*)d_in[14];
  const float* bn_gamma = (const float*)d_in[15];
  const float* bn_beta  = (const float*)d_in[16];
  const float* bn_mean  = (const float*)d_in[17];
  const float* bn_var   = (const float*)d_in[18];
  const float* gc_w = (const float*)d_in[19];
  const float* gc_b = (const float*)d_in[20];
  const float* gf1_w = (const float*)d_in[21];
  const float* gf1_b = (const float*)d_in[22];
  const float* gf2_w = (const float*)d_in[23];
  const float* gf2_b = (const float*)d_in[24];
  const float* p1_w = (const float*)d_in[25];
  const float* p1_b = (const float*)d_in[26];
  const float* p2_w = (const float*)d_in[27];
  const float* p2_b = (const float*)d_in[28];
  const float* p3_w = (const float*)d_in[29];
  const float* p3_b = (const float*)d_in[30];
  float* out = (float*)d_out;

  char* w = (char*)d_ws;
  size_t o = 0;
  auto carve = [&](size_t bytes)->char*{
    char* p = w + o; o += (bytes + 255) & ~(size_t)255; return p;
  };
  unsigned* xhb = (unsigned*)carve((size_t)N_NODES*64*4);
  float* hbuf   = (float*)carve((size_t)N_NODES*HID*4);
  float* ea_csr = (float*)carve((size_t)N_EDGES*3*4);
  float* eamean = (float*)carve((size_t)N_NODES*4*4);
  float* as_    = (float*)carve((size_t)N_NODES*4*4);
  float* ad_    = (float*)carve((size_t)N_NODES*4*4);
  int* deg      = (int*)carve((size_t)N_NODES*4);
  int* rowptr   = (int*)carve((size_t)(N_NODES+1)*4);
  int* fill     = (int*)carve((size_t)N_NODES*4);
  int* csr_src  = (int*)carve((size_t)N_EDGES*4);
  int* part     = (int*)carve(1024*4);
  float* mebuf  = (float*)carve(64*4);
  float* bnA    = (float*)carve((size_t)NLAYER*HID*4);
  float* bnS    = (float*)carve((size_t)NLAYER*HID*4);
  unsigned short* whi = (unsigned short*)carve(65536*2);
  unsigned short* wlo = (unsigned short*)carve(65536*2);
  int* gptr     = (int*)carve((size_t)(N_GRAPHS+1)*4);
  float* gfeat  = (float*)carve((size_t)N_GRAPHS*384*4);

  hipMemsetAsync(deg, 0, (size_t)N_NODES*4, stream);
  hipMemsetAsync(fill, 0, (size_t)N_NODES*4, stream);

  k_prep<<<1,256,0,stream>>>(gat_edge_w, att_edge, edge_w, edge_b, mebuf);
  k_bnfold<<<2,256,0,stream>>>(gat_bias, bn_gamma, bn_beta, bn_mean, bn_var, bnA, bnS);
  k_wswz<<<256,256,0,stream>>>(gat_lin_w, whi, wlo);
  k_hinit<<<N_NODES,128,0,stream>>>(x, node_w, node_b, hbuf);
  k_deg<<<(N_EDGES+255)/256,256,0,stream>>>(ei, deg);
  int nb = (N_NODES+1023)/1024;
  k_scan1<<<nb,256,0,stream>>>(deg, part);
  k_scan2<<<1,64,0,stream>>>(part, rowptr, nb);
  k_scan3<<<nb,256,0,stream>>>(deg, part, rowptr);
  k_fill<<<(N_EDGES+255)/256,256,0,stream>>>(ei, ea, rowptr, fill, csr_src, ea_csr);
  k_eamean<<<(N_NODES+255)/256,256,0,stream>>>(ea_csr, rowptr, eamean);

  for(int l=0;l<NLAYER;++l){
    k_gemm<<<(N_NODES+63)/64,256,0,stream>>>(hbuf, whi + l*16384, wlo + l*16384,
        att_src + l*128, att_dst + l*128, xhb, as_, ad_);
    k_aggr<<<(N_NODES+3)/4,256,0,stream>>>(xhb, as_, ad_, ea_csr, eamean, mebuf,
        rowptr, csr_src, bnA + l*128, bnS + l*128, hbuf, l);
  }

  k_gptr<<<(N_GRAPHS+256)/256,256,0,stream>>>(batch, gptr);
  k_pool<<<N_GRAPHS,128,0,stream>>>(hbuf, gptr, gfeat);
  k_head<<<N_GRAPHS,128,0,stream>>>(gfeat, gfin, gc_w, gc_b, gf1_w, gf1_b, gf2_w, gf2_b,
        p1_w, p1_b, p2_w, p2_b, p3_w, p3_b, out);
}